// Round 1
// baseline (934.835 us; speedup 1.0000x reference)
//
#include <hip/hip_runtime.h>
#include <hip/hip_bf16.h>
#include <stdint.h>

typedef __hip_bfloat16 bf16;
typedef __attribute__((ext_vector_type(8))) __bf16 bf16x8;
typedef __attribute__((ext_vector_type(4))) float f32x4;

__device__ __forceinline__ void gld16(void* lds, const void* g) {
  __builtin_amdgcn_global_load_lds(
      (const __attribute__((address_space(1))) void*)(uintptr_t)(g),
      (__attribute__((address_space(3))) void*)(uint32_t)(uintptr_t)(lds),
      16, 0, 0);
}

__device__ __forceinline__ uint16_t f2bf(float f) {
  union { bf16 h; uint16_t u; } x; x.h = __float2bfloat16(f); return x.u;
}
__device__ __forceinline__ float bf2f(uint16_t v) {
  union { uint32_t u; float f; } x; x.u = ((uint32_t)v) << 16; return x.f;
}
__device__ __forceinline__ float redmax16(float v) {
  v = fmaxf(v, __shfl_xor(v, 1)); v = fmaxf(v, __shfl_xor(v, 2));
  v = fmaxf(v, __shfl_xor(v, 4)); v = fmaxf(v, __shfl_xor(v, 8));
  return v;
}
__device__ __forceinline__ float redsum16(float v) {
  v += __shfl_xor(v, 1); v += __shfl_xor(v, 2);
  v += __shfl_xor(v, 4); v += __shfl_xor(v, 8);
  return v;
}

// ---------------- f32 -> bf16 cast (vectorized) ----------------
__global__ __launch_bounds__(256) void k_cast(const float4* __restrict__ in,
                                              uint2* __restrict__ out, int n4) {
  int i = blockIdx.x * 256 + threadIdx.x;
  if (i >= n4) return;
  float4 v = in[i];
  uint32_t a = ((uint32_t)f2bf(v.y) << 16) | f2bf(v.x);
  uint32_t b = ((uint32_t)f2bf(v.w) << 16) | f2bf(v.z);
  out[i] = make_uint2(a, b);
}

// ---------------- NT GEMM: C[m][n] = sum_k A[m][k]*B[n][k] + bias[n] -------
// 128x128 tile, BK=32, 4 waves (2x2 of 64x64), mfma 16x16x32 bf16.
template <int OUT_BF16>
__global__ __launch_bounds__(256) void k_gemm_bt(
    const bf16* __restrict__ A, const bf16* __restrict__ B,
    const float* __restrict__ bias, void* __restrict__ C,
    int M, int N, int K) {
  __shared__ __align__(16) bf16 As[128 * 32];
  __shared__ __align__(16) bf16 Bs[128 * 32];
  const int tid = threadIdx.x;
  const int lane = tid & 63;
  const int w = tid >> 6;
  const int lm = lane & 15;
  const int lg = lane >> 4;
  const size_t bm = (size_t)blockIdx.y * 128;
  const size_t bn = (size_t)blockIdx.x * 128;
  const int wr = (w >> 1) * 64;
  const int wc = (w & 1) * 64;

  f32x4 acc[4][4];
#pragma unroll
  for (int i = 0; i < 4; ++i)
#pragma unroll
    for (int j = 0; j < 4; ++j) acc[i][j] = (f32x4){0.f, 0.f, 0.f, 0.f};

  const int o0 = w * 1024 + lane * 16;
  for (int k0 = 0; k0 < K; k0 += 32) {
#pragma unroll
    for (int i = 0; i < 2; ++i) {
      const int o = o0 + i * 4096;
      const int row = o >> 6;      // 64B per row (32 bf16)
      const int cbyte = o & 63;
      gld16((char*)As + o, (const char*)(A + (bm + row) * K + k0) + cbyte);
      gld16((char*)Bs + o, (const char*)(B + (bn + row) * K + k0) + cbyte);
    }
    __syncthreads();
    bf16x8 af[4], bfr[4];
#pragma unroll
    for (int mi = 0; mi < 4; ++mi)
      af[mi] = *(const bf16x8*)(As + (wr + mi * 16 + lm) * 32 + lg * 8);
#pragma unroll
    for (int ni = 0; ni < 4; ++ni)
      bfr[ni] = *(const bf16x8*)(Bs + (wc + ni * 16 + lm) * 32 + lg * 8);
#pragma unroll
    for (int mi = 0; mi < 4; ++mi)
#pragma unroll
      for (int ni = 0; ni < 4; ++ni)
        acc[mi][ni] = __builtin_amdgcn_mfma_f32_16x16x32_bf16(
            af[mi], bfr[ni], acc[mi][ni], 0, 0, 0);
    __syncthreads();
  }

#pragma unroll
  for (int mi = 0; mi < 4; ++mi) {
#pragma unroll
    for (int ni = 0; ni < 4; ++ni) {
      const size_t col = bn + wc + ni * 16 + lm;
      const float bv = bias[col];
#pragma unroll
      for (int r = 0; r < 4; ++r) {
        const size_t row = bm + wr + mi * 16 + lg * 4 + r;
        const float v = acc[mi][ni][r] + bv;
        if (OUT_BF16)
          ((bf16*)C)[row * N + col] = __float2bfloat16(v);
        else
          ((float*)C)[row * N + col] = v;
      }
    }
  }
}

// ---------------- RoPE on Q: [b][t][h*128+d] -> [b][h][t][d] ----------------
__global__ __launch_bounds__(256) void k_rope_q(
    const uint32_t* __restrict__ qin, const float* __restrict__ fc,
    const float* __restrict__ fs, uint32_t* __restrict__ qout) {
  const int tid = blockIdx.x * 256 + threadIdx.x;  // 2*2048*32*64 pairs
  const int i = tid & 63;
  const int h = (tid >> 6) & 31;
  const int t = (tid >> 11) & 2047;
  const int b = tid >> 22;
  const uint32_t u = qin[tid];
  const float t0 = bf2f((uint16_t)(u & 0xffff));
  const float t1 = bf2f((uint16_t)(u >> 16));
  const float c = fc[t * 64 + i];
  const float s = fs[t * 64 + i];
  const float r0 = t0 * c - t1 * s;
  const float r1 = t0 * s + t1 * c;
  const uint32_t o = ((uint32_t)f2bf(r1) << 16) | f2bf(r0);
  qout[(((size_t)(b * 32 + h)) * 2048 + t) * 64 + i] = o;
}

// ---------------- RoPE on K part of KV: kv[b][t][kvh*128+d] -> [b][kvh][t][d]
__global__ __launch_bounds__(256) void k_rope_k(
    const uint32_t* __restrict__ kvin, const float* __restrict__ fc,
    const float* __restrict__ fs, uint32_t* __restrict__ kout) {
  const int tid = blockIdx.x * 256 + threadIdx.x;  // 2*2048*8*64 pairs
  const int i = tid & 63;
  const int kvh = (tid >> 6) & 7;
  const int t = (tid >> 9) & 2047;
  const int b = tid >> 20;
  const uint32_t u = kvin[((size_t)(b * 2048 + t)) * 1024 + kvh * 64 + i];
  const float t0 = bf2f((uint16_t)(u & 0xffff));
  const float t1 = bf2f((uint16_t)(u >> 16));
  const float c = fc[t * 64 + i];
  const float s = fs[t * 64 + i];
  const float r0 = t0 * c - t1 * s;
  const float r1 = t0 * s + t1 * c;
  const uint32_t o = ((uint32_t)f2bf(r1) << 16) | f2bf(r0);
  kout[(((size_t)(b * 8 + kvh)) * 2048 + t) * 64 + i] = o;
}

// ---------------- V transpose: kv v-part [b][t][1024+kvh*128+d] -> [b][kvh][d][t]
__global__ __launch_bounds__(256) void k_vt(const bf16* __restrict__ kv,
                                            bf16* __restrict__ vt) {
  __shared__ __align__(16) bf16 tile[64][130];
  const int bh = blockIdx.y;  // b*8+kvh
  const int b = bh >> 3, kvh = bh & 7;
  const int t0 = blockIdx.x * 64;
  const int tid = threadIdx.x;
  const int d0 = (tid & 15) * 8;
  const int tr = tid >> 4;
#pragma unroll
  for (int j = 0; j < 4; ++j) {
    const int trow = tr + j * 16;
    const bf16* src =
        kv + ((size_t)(b * 2048) + t0 + trow) * 2048 + 1024 + kvh * 128 + d0;
    uint4 v = *(const uint4*)src;
    uint32_t* dst = (uint32_t*)&tile[trow][d0];
    dst[0] = v.x; dst[1] = v.y; dst[2] = v.z; dst[3] = v.w;
  }
  __syncthreads();
  const int d = tid >> 1;
  const int th = (tid & 1) * 32;
  uint4* out = (uint4*)(vt + (((size_t)bh) * 128 + d) * 2048 + t0 + th);
  union { bf16 h; uint16_t u; } cv;
#pragma unroll
  for (int j = 0; j < 4; ++j) {
    uint32_t wds[4];
#pragma unroll
    for (int p = 0; p < 4; ++p) {
      cv.h = tile[th + j * 8 + p * 2][d];
      uint32_t lo = cv.u;
      cv.h = tile[th + j * 8 + p * 2 + 1][d];
      wds[p] = lo | ((uint32_t)cv.u << 16);
    }
    uint4 val; val.x = wds[0]; val.y = wds[1]; val.z = wds[2]; val.w = wds[3];
    out[j] = val;
  }
}

// ---------------- causal GQA flash attention ----------------
// grid (T/64, B*HEADS); 4 waves x 16 q-rows; 64-key tiles.
__global__ __launch_bounds__(256) void k_attn(
    const bf16* __restrict__ Q, const bf16* __restrict__ Kr,
    const bf16* __restrict__ Vt, bf16* __restrict__ Y) {
  constexpr int T = 2048;
  __shared__ __align__(16) bf16 Ks[64 * 128];   // [key][d], XOR-swizzled rows (256B)
  __shared__ __align__(16) bf16 Vts[128 * 64];  // [d][key], XOR-swizzled rows (128B)
  __shared__ __align__(16) bf16 Ps[4][16 * 64]; // per-wave P, swizzled rows (128B)

  const int tid = threadIdx.x;
  const int lane = tid & 63;
  const int w = tid >> 6;
  const int lm = lane & 15;
  const int lg = lane >> 4;
  const int hi = blockIdx.y;
  const int b = hi >> 5;
  const int h = hi & 31;
  const int kvh = h >> 2;
  const int q0 = blockIdx.x * 64;
  const int qw = q0 + w * 16;

  const bf16* qbase = Q + (((size_t)(b * 32 + h)) * T + qw) * 128;
  bf16x8 qf[4];
#pragma unroll
  for (int c = 0; c < 4; ++c)
    qf[c] = *(const bf16x8*)(qbase + lm * 128 + c * 32 + lg * 8);

  f32x4 oacc[8];
#pragma unroll
  for (int i = 0; i < 8; ++i) oacc[i] = (f32x4){0.f, 0.f, 0.f, 0.f};
  float mrow[4] = {-1e30f, -1e30f, -1e30f, -1e30f};
  float lrow[4] = {0.f, 0.f, 0.f, 0.f};

  const char* kg = (const char*)(Kr + ((size_t)(b * 8 + kvh)) * T * 128);
  const char* vg = (const char*)(Vt + ((size_t)(b * 8 + kvh)) * 128 * T);

  const int ntiles = blockIdx.x + 1;
  for (int it = 0; it < ntiles; ++it) {
    const int kt = it * 64;
    __syncthreads();
#pragma unroll
    for (int i = 0; i < 4; ++i) {
      const int o = i * 4096 + w * 1024 + lane * 16;
      {
        const int row = o >> 8;
        const int cb = (o & 255) ^ ((row & 7) << 4);  // pre-swizzle source
        gld16((char*)Ks + o, kg + ((size_t)(kt + row) * 128) * 2 + cb);
      }
      {
        const int row = o >> 7;
        const int cb = (o & 127) ^ ((row & 7) << 4);
        gld16((char*)Vts + o, vg + ((size_t)row * T + kt) * 2 + cb);
      }
    }
    __syncthreads();

    // S = Q K^T (4 key sub-tiles of 16)
    f32x4 sf[4];
#pragma unroll
    for (int s = 0; s < 4; ++s) {
      f32x4 a = (f32x4){0.f, 0.f, 0.f, 0.f};
      const int key = s * 16 + lm;
#pragma unroll
      for (int c = 0; c < 4; ++c) {
        int byte = key * 256 + c * 64 + lg * 16;
        byte ^= (key & 7) << 4;
        bf16x8 kf = *(const bf16x8*)((const char*)Ks + byte);
        a = __builtin_amdgcn_mfma_f32_16x16x32_bf16(qf[c], kf, a, 0, 0, 0);
      }
      sf[s] = a;
    }

    const float scale = 0.08838834764831845f;
    float tmax[4] = {-1e30f, -1e30f, -1e30f, -1e30f};
#pragma unroll
    for (int s = 0; s < 4; ++s) {
      const int key = kt + s * 16 + lm;
#pragma unroll
      for (int r = 0; r < 4; ++r) {
        const int qrow = qw + lg * 4 + r;
        float v = sf[s][r] * scale;
        v = (key <= qrow) ? v : -1e30f;
        sf[s][r] = v;
        tmax[r] = fmaxf(tmax[r], v);
      }
    }
    float alpha[4];
#pragma unroll
    for (int r = 0; r < 4; ++r) {
      const float tm = redmax16(tmax[r]);
      const float mn = fmaxf(mrow[r], tm);
      alpha[r] = __expf(mrow[r] - mn);
      mrow[r] = mn;
    }
    float psum[4] = {0.f, 0.f, 0.f, 0.f};
#pragma unroll
    for (int s = 0; s < 4; ++s) {
#pragma unroll
      for (int r = 0; r < 4; ++r) {
        const float p = __expf(sf[s][r] - mrow[r]);
        psum[r] += p;
        const int prow = lg * 4 + r;
        int byte = prow * 128 + (s * 16 + lm) * 2;
        byte ^= (prow & 7) << 4;
        *(uint16_t*)((char*)Ps[w] + byte) = f2bf(p);
      }
    }
#pragma unroll
    for (int r = 0; r < 4; ++r) {
      lrow[r] = lrow[r] * alpha[r] + redsum16(psum[r]);
#pragma unroll
      for (int i = 0; i < 8; ++i) oacc[i][r] *= alpha[r];
    }

    // O += P V  (A-frags from per-wave Ps, B-frags from Vts)
    bf16x8 pf[2];
#pragma unroll
    for (int ks = 0; ks < 2; ++ks) {
      int byte = lm * 128 + (ks * 32 + lg * 8) * 2;
      byte ^= (lm & 7) << 4;
      pf[ks] = *(const bf16x8*)((const char*)Ps[w] + byte);
    }
#pragma unroll
    for (int dd = 0; dd < 8; ++dd) {
#pragma unroll
      for (int ks = 0; ks < 2; ++ks) {
        const int vrow = dd * 16 + lm;
        int byte = vrow * 128 + (ks * 32 + lg * 8) * 2;
        byte ^= (vrow & 7) << 4;
        bf16x8 vf = *(const bf16x8*)((const char*)Vts + byte);
        oacc[dd] = __builtin_amdgcn_mfma_f32_16x16x32_bf16(pf[ks], vf, oacc[dd], 0, 0, 0);
      }
    }
  }

#pragma unroll
  for (int r = 0; r < 4; ++r) {
    const float inv = 1.0f / lrow[r];
    const int t = qw + lg * 4 + r;
    bf16* yb = Y + ((size_t)(b * T + t)) * 4096 + h * 128;
#pragma unroll
    for (int dd = 0; dd < 8; ++dd)
      yb[dd * 16 + lm] = __float2bfloat16(oacc[dd][r] * inv);
  }
}

// ---------------- launch ----------------
extern "C" void kernel_launch(void* const* d_in, const int* in_sizes, int n_in,
                              void* d_out, int out_size, void* d_ws, size_t ws_size,
                              hipStream_t stream) {
  const float* x = (const float*)d_in[0];
  const float* fcos = (const float*)d_in[1];
  const float* fsin = (const float*)d_in[2];
  const float* wq = (const float*)d_in[3];
  const float* bq = (const float*)d_in[4];
  const float* wkv = (const float*)d_in[5];
  const float* bkv = (const float*)d_in[6];
  const float* wp = (const float*)d_in[7];
  const float* bp = (const float*)d_in[8];

  char* ws = (char*)d_ws;
  size_t off = 0;
  auto alloc = [&](size_t bytes) {
    char* p = ws + off;
    off += (bytes + 255) & ~(size_t)255;
    return p;
  };
  bf16* xb = (bf16*)alloc(16777216ull * 2);    // x bf16 [b][t][4096]
  bf16* wqb = (bf16*)alloc(16777216ull * 2);   // w_q bf16 [4096][4096]
  bf16* wkvb = (bf16*)alloc(8388608ull * 2);   // w_kv bf16 [2048][4096]
  bf16* wpb = (bf16*)alloc(16777216ull * 2);   // proj bf16 [4096][4096]
  bf16* qb = (bf16*)alloc(16777216ull * 2);    // q pre-rope [b][t][4096]; reused as Y
  bf16* kvb = (bf16*)alloc(8388608ull * 2);    // kv pre-rope [b][t][2048]
  bf16* qr = (bf16*)alloc(16777216ull * 2);    // roped Q [b][h][t][128]
  bf16* kr = (bf16*)alloc(4194304ull * 2);     // roped K [b][kvh][t][128]
  bf16* vt = (bf16*)alloc(4194304ull * 2);     // V^T [b][kvh][128][t]
  bf16* yb = qb;                               // attn out [b][t][4096] (aliases qb)

  k_cast<<<16384, 256, 0, stream>>>((const float4*)x, (uint2*)xb, 4194304);
  k_cast<<<16384, 256, 0, stream>>>((const float4*)wq, (uint2*)wqb, 4194304);
  k_cast<<<8192, 256, 0, stream>>>((const float4*)wkv, (uint2*)wkvb, 2097152);
  k_cast<<<16384, 256, 0, stream>>>((const float4*)wp, (uint2*)wpb, 4194304);

  k_gemm_bt<1><<<dim3(32, 32), 256, 0, stream>>>(xb, wqb, bq, qb, 4096, 4096, 4096);
  k_gemm_bt<1><<<dim3(16, 32), 256, 0, stream>>>(xb, wkvb, bkv, kvb, 4096, 2048, 4096);

  k_rope_q<<<32768, 256, 0, stream>>>((const uint32_t*)qb, fcos, fsin, (uint32_t*)qr);
  k_rope_k<<<8192, 256, 0, stream>>>((const uint32_t*)kvb, fcos, fsin, (uint32_t*)kr);
  k_vt<<<dim3(32, 16), 256, 0, stream>>>(kvb, vt);

  k_attn<<<dim3(32, 64), 256, 0, stream>>>(qr, kr, vt, yb);

  k_gemm_bt<0><<<dim3(32, 32), 256, 0, stream>>>(yb, wpb, bp, d_out, 4096, 4096, 4096);
}

// Round 2
// 782.545 us; speedup vs baseline: 1.1946x; 1.1946x over previous
//
#include <hip/hip_runtime.h>
#include <hip/hip_bf16.h>
#include <stdint.h>

typedef __hip_bfloat16 bf16;
typedef __attribute__((ext_vector_type(8))) __bf16 bf16x8;
typedef __attribute__((ext_vector_type(4))) float f32x4;

__device__ __forceinline__ void gld16(void* lds, const void* g) {
  __builtin_amdgcn_global_load_lds(
      (const __attribute__((address_space(1))) void*)(uintptr_t)(g),
      (__attribute__((address_space(3))) void*)(uint32_t)(uintptr_t)(lds),
      16, 0, 0);
}

__device__ __forceinline__ uint16_t f2bf(float f) {
  union { bf16 h; uint16_t u; } x; x.h = __float2bfloat16(f); return x.u;
}
__device__ __forceinline__ float bf2f(uint16_t v) {
  union { uint32_t u; float f; } x; x.u = ((uint32_t)v) << 16; return x.f;
}
__device__ __forceinline__ float redmax16(float v) {
  v = fmaxf(v, __shfl_xor(v, 1)); v = fmaxf(v, __shfl_xor(v, 2));
  v = fmaxf(v, __shfl_xor(v, 4)); v = fmaxf(v, __shfl_xor(v, 8));
  return v;
}
__device__ __forceinline__ float redsum16(float v) {
  v += __shfl_xor(v, 1); v += __shfl_xor(v, 2);
  v += __shfl_xor(v, 4); v += __shfl_xor(v, 8);
  return v;
}

// ---------------- f32 -> bf16 cast (vectorized) ----------------
__global__ __launch_bounds__(256) void k_cast(const float4* __restrict__ in,
                                              uint2* __restrict__ out, int n4) {
  int i = blockIdx.x * 256 + threadIdx.x;
  if (i >= n4) return;
  float4 v = in[i];
  uint32_t a = ((uint32_t)f2bf(v.y) << 16) | f2bf(v.x);
  uint32_t b = ((uint32_t)f2bf(v.w) << 16) | f2bf(v.z);
  out[i] = make_uint2(a, b);
}

// ---------------- NT GEMM: C[m][n] = sum_k A[m][k]*B[n][k] + bias[n] -------
// 128x128 tile, BK=32, 4 waves (2x2 of 64x64), mfma 16x16x32 bf16.
template <int OUT_BF16>
__global__ __launch_bounds__(256) void k_gemm_bt(
    const bf16* __restrict__ A, const bf16* __restrict__ B,
    const float* __restrict__ bias, void* __restrict__ C,
    int M, int N, int K) {
  __shared__ __align__(16) bf16 As[128 * 32];
  __shared__ __align__(16) bf16 Bs[128 * 32];
  const int tid = threadIdx.x;
  const int lane = tid & 63;
  const int w = tid >> 6;
  const int lm = lane & 15;
  const int lg = lane >> 4;
  const size_t bm = (size_t)blockIdx.y * 128;
  const size_t bn = (size_t)blockIdx.x * 128;
  const int wr = (w >> 1) * 64;
  const int wc = (w & 1) * 64;

  f32x4 acc[4][4];
#pragma unroll
  for (int i = 0; i < 4; ++i)
#pragma unroll
    for (int j = 0; j < 4; ++j) acc[i][j] = (f32x4){0.f, 0.f, 0.f, 0.f};

  const int o0 = w * 1024 + lane * 16;
  for (int k0 = 0; k0 < K; k0 += 32) {
#pragma unroll
    for (int i = 0; i < 2; ++i) {
      const int o = o0 + i * 4096;
      const int row = o >> 6;      // 64B per row (32 bf16)
      const int cbyte = o & 63;
      gld16((char*)As + o, (const char*)(A + (bm + row) * K + k0) + cbyte);
      gld16((char*)Bs + o, (const char*)(B + (bn + row) * K + k0) + cbyte);
    }
    __syncthreads();
    bf16x8 af[4], bfr[4];
#pragma unroll
    for (int mi = 0; mi < 4; ++mi)
      af[mi] = *(const bf16x8*)(As + (wr + mi * 16 + lm) * 32 + lg * 8);
#pragma unroll
    for (int ni = 0; ni < 4; ++ni)
      bfr[ni] = *(const bf16x8*)(Bs + (wc + ni * 16 + lm) * 32 + lg * 8);
#pragma unroll
    for (int mi = 0; mi < 4; ++mi)
#pragma unroll
      for (int ni = 0; ni < 4; ++ni)
        acc[mi][ni] = __builtin_amdgcn_mfma_f32_16x16x32_bf16(
            af[mi], bfr[ni], acc[mi][ni], 0, 0, 0);
    __syncthreads();
  }

#pragma unroll
  for (int mi = 0; mi < 4; ++mi) {
#pragma unroll
    for (int ni = 0; ni < 4; ++ni) {
      const size_t col = bn + wc + ni * 16 + lm;
      const float bv = bias[col];
#pragma unroll
      for (int r = 0; r < 4; ++r) {
        const size_t row = bm + wr + mi * 16 + lg * 4 + r;
        const float v = acc[mi][ni][r] + bv;
        if (OUT_BF16)
          ((bf16*)C)[row * N + col] = __float2bfloat16(v);
        else
          ((float*)C)[row * N + col] = v;
      }
    }
  }
}

// ---------------- RoPE on Q: [b][t][h*128+d] -> [b][h][t][d] ----------------
__global__ __launch_bounds__(256) void k_rope_q(
    const uint32_t* __restrict__ qin, const float* __restrict__ fc,
    const float* __restrict__ fs, uint32_t* __restrict__ qout) {
  const int tid = blockIdx.x * 256 + threadIdx.x;  // 2*2048*32*64 pairs
  const int i = tid & 63;
  const int h = (tid >> 6) & 31;
  const int t = (tid >> 11) & 2047;
  const int b = tid >> 22;
  const uint32_t u = qin[tid];
  const float t0 = bf2f((uint16_t)(u & 0xffff));
  const float t1 = bf2f((uint16_t)(u >> 16));
  const float c = fc[t * 64 + i];
  const float s = fs[t * 64 + i];
  const float r0 = t0 * c - t1 * s;
  const float r1 = t0 * s + t1 * c;
  const uint32_t o = ((uint32_t)f2bf(r1) << 16) | f2bf(r0);
  qout[(((size_t)(b * 32 + h)) * 2048 + t) * 64 + i] = o;
}

// ---------------- RoPE on K part of KV: kv[b][t][kvh*128+d] -> [b][kvh][t][d]
__global__ __launch_bounds__(256) void k_rope_k(
    const uint32_t* __restrict__ kvin, const float* __restrict__ fc,
    const float* __restrict__ fs, uint32_t* __restrict__ kout) {
  const int tid = blockIdx.x * 256 + threadIdx.x;  // 2*2048*8*64 pairs
  const int i = tid & 63;
  const int kvh = (tid >> 6) & 7;
  const int t = (tid >> 9) & 2047;
  const int b = tid >> 20;
  const uint32_t u = kvin[((size_t)(b * 2048 + t)) * 1024 + kvh * 64 + i];
  const float t0 = bf2f((uint16_t)(u & 0xffff));
  const float t1 = bf2f((uint16_t)(u >> 16));
  const float c = fc[t * 64 + i];
  const float s = fs[t * 64 + i];
  const float r0 = t0 * c - t1 * s;
  const float r1 = t0 * s + t1 * c;
  const uint32_t o = ((uint32_t)f2bf(r1) << 16) | f2bf(r0);
  kout[(((size_t)(b * 8 + kvh)) * 2048 + t) * 64 + i] = o;
}

// ---------------- V transpose: kv v-part [b][t][1024+kvh*128+d] -> [b][kvh][d][t]
__global__ __launch_bounds__(256) void k_vt(const bf16* __restrict__ kv,
                                            bf16* __restrict__ vt) {
  __shared__ __align__(16) bf16 tile[64][130];
  const int bh = blockIdx.y;  // b*8+kvh
  const int b = bh >> 3, kvh = bh & 7;
  const int t0 = blockIdx.x * 64;
  const int tid = threadIdx.x;
  const int d0 = (tid & 15) * 8;
  const int tr = tid >> 4;
#pragma unroll
  for (int j = 0; j < 4; ++j) {
    const int trow = tr + j * 16;
    const bf16* src =
        kv + ((size_t)(b * 2048) + t0 + trow) * 2048 + 1024 + kvh * 128 + d0;
    uint4 v = *(const uint4*)src;
    uint32_t* dst = (uint32_t*)&tile[trow][d0];
    dst[0] = v.x; dst[1] = v.y; dst[2] = v.z; dst[3] = v.w;
  }
  __syncthreads();
  const int d = tid >> 1;
  const int th = (tid & 1) * 32;
  uint4* out = (uint4*)(vt + (((size_t)bh) * 128 + d) * 2048 + t0 + th);
  union { bf16 h; uint16_t u; } cv;
#pragma unroll
  for (int j = 0; j < 4; ++j) {
    uint32_t wds[4];
#pragma unroll
    for (int p = 0; p < 4; ++p) {
      cv.h = tile[th + j * 8 + p * 2][d];
      uint32_t lo = cv.u;
      cv.h = tile[th + j * 8 + p * 2 + 1][d];
      wds[p] = lo | ((uint32_t)cv.u << 16);
    }
    uint4 val; val.x = wds[0]; val.y = wds[1]; val.z = wds[2]; val.w = wds[3];
    out[j] = val;
  }
}

// ---------------- causal GQA flash attention ----------------
// 1D grid of 2048 blocks, heavy-first: qi = 31 - n/64 so the 32-tile blocks
// dispatch first and light blocks backfill (load balancing).
__global__ __launch_bounds__(256) void k_attn(
    const bf16* __restrict__ Q, const bf16* __restrict__ Kr,
    const bf16* __restrict__ Vt, bf16* __restrict__ Y) {
  constexpr int T = 2048;
  __shared__ __align__(16) bf16 Ks[64 * 128];   // [key][d], XOR-swizzled rows (256B)
  __shared__ __align__(16) bf16 Vts[128 * 64];  // [d][key], XOR-swizzled rows (128B)
  __shared__ __align__(16) bf16 Ps[4][16 * 64]; // per-wave P, swizzled rows (128B)

  const int tid = threadIdx.x;
  const int lane = tid & 63;
  const int w = tid >> 6;
  const int lm = lane & 15;
  const int lg = lane >> 4;
  const int n = blockIdx.x;
  const int qi = 31 - (n >> 6);  // heavy-first
  const int hi = n & 63;
  const int b = hi >> 5;
  const int h = hi & 31;
  const int kvh = h >> 2;
  const int q0 = qi * 64;
  const int qw = q0 + w * 16;

  const bf16* qbase = Q + (((size_t)(b * 32 + h)) * T + qw) * 128;
  bf16x8 qf[4];
#pragma unroll
  for (int c = 0; c < 4; ++c)
    qf[c] = *(const bf16x8*)(qbase + lm * 128 + c * 32 + lg * 8);

  f32x4 oacc[8];
#pragma unroll
  for (int i = 0; i < 8; ++i) oacc[i] = (f32x4){0.f, 0.f, 0.f, 0.f};
  float mrow[4] = {-1e30f, -1e30f, -1e30f, -1e30f};
  float lrow[4] = {0.f, 0.f, 0.f, 0.f};

  const char* kg = (const char*)(Kr + ((size_t)(b * 8 + kvh)) * T * 128);
  const char* vg = (const char*)(Vt + ((size_t)(b * 8 + kvh)) * 128 * T);

  const int ntiles = qi + 1;
  for (int it = 0; it < ntiles; ++it) {
    const int kt = it * 64;
    __syncthreads();
#pragma unroll
    for (int i = 0; i < 4; ++i) {
      const int o = i * 4096 + w * 1024 + lane * 16;
      {
        const int row = o >> 8;
        const int cb = (o & 255) ^ ((row & 7) << 4);  // pre-swizzle source
        gld16((char*)Ks + o, kg + ((size_t)(kt + row) * 128) * 2 + cb);
      }
      {
        const int row = o >> 7;
        const int cb = (o & 127) ^ ((row & 7) << 4);
        gld16((char*)Vts + o, vg + ((size_t)row * T + kt) * 2 + cb);
      }
    }
    __syncthreads();

    // S = Q K^T (4 key sub-tiles of 16)
    f32x4 sf[4];
#pragma unroll
    for (int s = 0; s < 4; ++s) {
      f32x4 a = (f32x4){0.f, 0.f, 0.f, 0.f};
      const int key = s * 16 + lm;
#pragma unroll
      for (int c = 0; c < 4; ++c) {
        int byte = key * 256 + c * 64 + lg * 16;
        byte ^= (key & 7) << 4;
        bf16x8 kf = *(const bf16x8*)((const char*)Ks + byte);
        a = __builtin_amdgcn_mfma_f32_16x16x32_bf16(qf[c], kf, a, 0, 0, 0);
      }
      sf[s] = a;
    }

    const float scale = 0.08838834764831845f;
    float tmax[4] = {-1e30f, -1e30f, -1e30f, -1e30f};
#pragma unroll
    for (int s = 0; s < 4; ++s) {
      const int key = kt + s * 16 + lm;
#pragma unroll
      for (int r = 0; r < 4; ++r) {
        const int qrow = qw + lg * 4 + r;
        float v = sf[s][r] * scale;
        v = (key <= qrow) ? v : -1e30f;
        sf[s][r] = v;
        tmax[r] = fmaxf(tmax[r], v);
      }
    }
    float alpha[4];
#pragma unroll
    for (int r = 0; r < 4; ++r) {
      const float tm = redmax16(tmax[r]);
      const float mn = fmaxf(mrow[r], tm);
      alpha[r] = __expf(mrow[r] - mn);
      mrow[r] = mn;
    }
    float psum[4] = {0.f, 0.f, 0.f, 0.f};
#pragma unroll
    for (int s = 0; s < 4; ++s) {
#pragma unroll
      for (int r = 0; r < 4; ++r) {
        const float p = __expf(sf[s][r] - mrow[r]);
        psum[r] += p;
        const int prow = lg * 4 + r;
        int byte = prow * 128 + (s * 16 + lm) * 2;
        byte ^= (prow & 7) << 4;
        *(uint16_t*)((char*)Ps[w] + byte) = f2bf(p);
      }
    }
#pragma unroll
    for (int r = 0; r < 4; ++r) {
      lrow[r] = lrow[r] * alpha[r] + redsum16(psum[r]);
#pragma unroll
      for (int i = 0; i < 8; ++i) oacc[i][r] *= alpha[r];
    }

    // O += P V  (A-frags from per-wave Ps, B-frags from Vts)
    bf16x8 pf[2];
#pragma unroll
    for (int ks = 0; ks < 2; ++ks) {
      int byte = lm * 128 + (ks * 32 + lg * 8) * 2;
      byte ^= (lm & 7) << 4;
      pf[ks] = *(const bf16x8*)((const char*)Ps[w] + byte);
    }
#pragma unroll
    for (int dd = 0; dd < 8; ++dd) {
#pragma unroll
      for (int ks = 0; ks < 2; ++ks) {
        const int vrow = dd * 16 + lm;
        int byte = vrow * 128 + (ks * 32 + lg * 8) * 2;
        byte ^= (vrow & 7) << 4;
        bf16x8 vf = *(const bf16x8*)((const char*)Vts + byte);
        oacc[dd] = __builtin_amdgcn_mfma_f32_16x16x32_bf16(pf[ks], vf, oacc[dd], 0, 0, 0);
      }
    }
  }

#pragma unroll
  for (int r = 0; r < 4; ++r) {
    const float inv = 1.0f / lrow[r];
    const int t = qw + lg * 4 + r;
    bf16* yb = Y + ((size_t)(b * T + t)) * 4096 + h * 128;
#pragma unroll
    for (int dd = 0; dd < 8; ++dd)
      yb[dd * 16 + lm] = __float2bfloat16(oacc[dd][r] * inv);
  }
}

// ---------------- launch ----------------
extern "C" void kernel_launch(void* const* d_in, const int* in_sizes, int n_in,
                              void* d_out, int out_size, void* d_ws, size_t ws_size,
                              hipStream_t stream) {
  const float* x = (const float*)d_in[0];
  const float* fcos = (const float*)d_in[1];
  const float* fsin = (const float*)d_in[2];
  const float* wq = (const float*)d_in[3];
  const float* bq = (const float*)d_in[4];
  const float* wkv = (const float*)d_in[5];
  const float* bkv = (const float*)d_in[6];
  const float* wp = (const float*)d_in[7];
  const float* bp = (const float*)d_in[8];

  char* ws = (char*)d_ws;
  size_t off = 0;
  auto alloc = [&](size_t bytes) {
    char* p = ws + off;
    off += (bytes + 255) & ~(size_t)255;
    return p;
  };
  bf16* xb = (bf16*)alloc(16777216ull * 2);    // x bf16 [b][t][4096]
  bf16* wqb = (bf16*)alloc(16777216ull * 2);   // w_q bf16 [4096][4096]
  bf16* wkvb = (bf16*)alloc(8388608ull * 2);   // w_kv bf16 [2048][4096]
  bf16* wpb = (bf16*)alloc(16777216ull * 2);   // proj bf16 [4096][4096]
  bf16* qb = (bf16*)alloc(16777216ull * 2);    // q pre-rope [b][t][4096]; reused as Y
  bf16* kvb = (bf16*)alloc(8388608ull * 2);    // kv pre-rope [b][t][2048]
  bf16* qr = (bf16*)alloc(16777216ull * 2);    // roped Q [b][h][t][128]
  bf16* kr = (bf16*)alloc(4194304ull * 2);     // roped K [b][kvh][t][128]
  bf16* vt = (bf16*)alloc(4194304ull * 2);     // V^T [b][kvh][128][t]
  bf16* yb = qb;                               // attn out [b][t][4096] (aliases qb)

  k_cast<<<16384, 256, 0, stream>>>((const float4*)x, (uint2*)xb, 4194304);
  k_cast<<<16384, 256, 0, stream>>>((const float4*)wq, (uint2*)wqb, 4194304);
  k_cast<<<8192, 256, 0, stream>>>((const float4*)wkv, (uint2*)wkvb, 2097152);
  k_cast<<<16384, 256, 0, stream>>>((const float4*)wp, (uint2*)wpb, 4194304);

  k_gemm_bt<1><<<dim3(32, 32), 256, 0, stream>>>(xb, wqb, bq, qb, 4096, 4096, 4096);
  k_gemm_bt<1><<<dim3(16, 32), 256, 0, stream>>>(xb, wkvb, bkv, kvb, 4096, 2048, 4096);

  k_rope_q<<<32768, 256, 0, stream>>>((const uint32_t*)qb, fcos, fsin, (uint32_t*)qr);
  k_rope_k<<<8192, 256, 0, stream>>>((const uint32_t*)kvb, fcos, fsin, (uint32_t*)kr);
  k_vt<<<dim3(32, 16), 256, 0, stream>>>(kvb, vt);

  k_attn<<<2048, 256, 0, stream>>>(qr, kr, vt, yb);

  k_gemm_bt<0><<<dim3(32, 32), 256, 0, stream>>>(yb, wpb, bp, d_out, 4096, 4096, 4096);
}

// Round 4
// 655.970 us; speedup vs baseline: 1.4251x; 1.1930x over previous
//
#include <hip/hip_runtime.h>
#include <hip/hip_bf16.h>
#include <stdint.h>

typedef __hip_bfloat16 bf16;
typedef __attribute__((ext_vector_type(8))) __bf16 bf16x8;
typedef __attribute__((ext_vector_type(4))) float f32x4;

__device__ __forceinline__ void gld16(void* lds, const void* g) {
  __builtin_amdgcn_global_load_lds(
      (const __attribute__((address_space(1))) void*)(uintptr_t)(g),
      (__attribute__((address_space(3))) void*)(uint32_t)(uintptr_t)(lds),
      16, 0, 0);
}

__device__ __forceinline__ uint16_t f2bf(float f) {
  union { bf16 h; uint16_t u; } x; x.h = __float2bfloat16(f); return x.u;
}
__device__ __forceinline__ float bf2f(uint16_t v) {
  union { uint32_t u; float f; } x; x.u = ((uint32_t)v) << 16; return x.f;
}
__device__ __forceinline__ float redmax16(float v) {
  v = fmaxf(v, __shfl_xor(v, 1)); v = fmaxf(v, __shfl_xor(v, 2));
  v = fmaxf(v, __shfl_xor(v, 4)); v = fmaxf(v, __shfl_xor(v, 8));
  return v;
}
__device__ __forceinline__ float redsum16(float v) {
  v += __shfl_xor(v, 1); v += __shfl_xor(v, 2);
  v += __shfl_xor(v, 4); v += __shfl_xor(v, 8);
  return v;
}

// ---------------- f32 -> bf16 cast (vectorized) ----------------
__global__ __launch_bounds__(256) void k_cast(const float4* __restrict__ in,
                                              uint2* __restrict__ out, int n4) {
  int i = blockIdx.x * 256 + threadIdx.x;
  if (i >= n4) return;
  float4 v = in[i];
  uint32_t a = ((uint32_t)f2bf(v.y) << 16) | f2bf(v.x);
  uint32_t b = ((uint32_t)f2bf(v.w) << 16) | f2bf(v.z);
  out[i] = make_uint2(a, b);
}

// ---------------- 256x256 8-phase NT GEMM ----------------
// C[m][n] = sum_k A[m][k]*B[n][k] + bias[n].  BK=64, 8 waves (2Mx4N),
// 512 threads, 2 K-tile LDS slots (128KiB), counted vmcnt(8), T2 swizzle,
// T5 setprio.  Grid: 1D nwg = (N/256)*(M/256), XCD-chunk swizzled.
template <int OUT_BF16>
__global__ __launch_bounds__(512, 2) void k_gemm256(
    const bf16* __restrict__ A, const bf16* __restrict__ B,
    const float* __restrict__ bias, void* __restrict__ C,
    int M, int N, int K, int gx) {
  __shared__ __align__(16) char lds[131072];  // [2 slots][A 32KB | B 32KB]
  const int tid = threadIdx.x;
  const int lane = tid & 63;
  const int w = tid >> 6;   // 0..7
  const int wm = w >> 2;    // 0..1  (M half: 128 rows)
  const int wn = w & 3;     // 0..3  (N quarter: 64 cols)
  const int lm = lane & 15;
  const int lg = lane >> 4;

  // XCD-chunk block swizzle (nwg % 8 == 0 for all our grids)
  const int nwg = gridDim.x;
  const int cpx = nwg >> 3;
  const int bid0 = blockIdx.x;
  const int bid = (bid0 & 7) * cpx + (bid0 >> 3);
  const int bx = bid % gx;
  const int by = bid / gx;
  const size_t bm = (size_t)by * 256;
  const size_t bn = (size_t)bx * 256;

  // staging: 8 x gld16 per K-tile; thread stages row srow (of 64-row group j),
  // 16B at swizzled in-row byte scb.  LDS dest is linear (rule #21: swizzle
  // the SOURCE, linear dest, swizzle on read).
  const int srow = tid >> 3;                              // 0..63
  const int scb = ((tid & 7) * 16) ^ ((srow & 7) << 4);   // swizzled byte-in-row
  const char* asrc[4];
  const char* bsrc[4];
#pragma unroll
  for (int j = 0; j < 4; ++j) {
    asrc[j] = (const char*)(A + (bm + j * 64 + srow) * K) + scb;
    bsrc[j] = (const char*)(B + (bn + j * 64 + srow) * K) + scb;
  }
  const int ldst = tid * 16;

  // per-lane swizzled column bytes for ds_read_b128 (row&7 == lm&7)
  // K-half 0 at row-bytes [0,64), half 1 at [64,128): half-1 addr = half-0 ^ 64
  const int colb0 = (lg * 16) ^ ((lm & 7) << 4);
  const int colb1 = colb0 ^ 64;

  f32x4 acc[8][4];
#pragma unroll
  for (int i = 0; i < 8; ++i)
#pragma unroll
    for (int j = 0; j < 4; ++j) acc[i][j] = (f32x4){0.f, 0.f, 0.f, 0.f};

  const int NT = K >> 6;  // K-tiles of 64

  // prologue: stage tile 0 -> slot 0
  {
    char* la = lds;
    char* lb = lds + 32768;
#pragma unroll
    for (int j = 0; j < 4; ++j) {
      gld16(la + j * 8192 + ldst, asrc[j]);
      gld16(lb + j * 8192 + ldst, bsrc[j]);
    }
  }

  for (int t = 0; t < NT; ++t) {
    const int slot = t & 1;
    if (t + 1 < NT) {
      // stage tile t+1 into the other slot; its loads stay in flight
      char* la = lds + (slot ^ 1) * 65536;
      char* lb = la + 32768;
      const size_t ko = (size_t)(t + 1) * 128;  // bytes: 64 cols * 2B
#pragma unroll
      for (int j = 0; j < 4; ++j) {
        gld16(la + j * 8192 + ldst, asrc[j] + ko);
        gld16(lb + j * 8192 + ldst, bsrc[j] + ko);
      }
      asm volatile("s_waitcnt vmcnt(8)" ::: "memory");  // tile t landed
    } else {
      asm volatile("s_waitcnt vmcnt(0)" ::: "memory");
    }
    __builtin_amdgcn_s_barrier();  // all waves' tile-t loads landed

    const char* la = lds + slot * 65536;
    const char* lb = la + 32768;
    bf16x8 bfrag[4][2];

#pragma unroll
    for (int p = 0; p < 4; ++p) {
      // phase-p ds_reads: A frags mi = 2p, 2p+1 (+ all B frags in phase 0)
      if (p == 0) {
#pragma unroll
        for (int ni = 0; ni < 4; ++ni) {
          const int br = wn * 64 + ni * 16 + lm;
          bfrag[ni][0] = *(const bf16x8*)(lb + br * 128 + colb0);
          bfrag[ni][1] = *(const bf16x8*)(lb + br * 128 + colb1);
        }
      }
      bf16x8 af[2][2];
#pragma unroll
      for (int q = 0; q < 2; ++q) {
        const int ar = wm * 128 + (2 * p + q) * 16 + lm;
        af[q][0] = *(const bf16x8*)(la + ar * 128 + colb0);
        af[q][1] = *(const bf16x8*)(la + ar * 128 + colb1);
      }
      __builtin_amdgcn_s_barrier();
      asm volatile("s_waitcnt lgkmcnt(0)" ::: "memory");
      __builtin_amdgcn_sched_barrier(0);
      __builtin_amdgcn_s_setprio(1);
#pragma unroll
      for (int q = 0; q < 2; ++q)
#pragma unroll
        for (int ni = 0; ni < 4; ++ni) {
          acc[2 * p + q][ni] = __builtin_amdgcn_mfma_f32_16x16x32_bf16(
              af[q][0], bfrag[ni][0], acc[2 * p + q][ni], 0, 0, 0);
          acc[2 * p + q][ni] = __builtin_amdgcn_mfma_f32_16x16x32_bf16(
              af[q][1], bfrag[ni][1], acc[2 * p + q][ni], 0, 0, 0);
        }
      __builtin_amdgcn_s_setprio(0);
      __builtin_amdgcn_s_barrier();
    }
  }

  // epilogue
#pragma unroll
  for (int ni = 0; ni < 4; ++ni) {
    const size_t col = bn + wn * 64 + ni * 16 + lm;
    const float bv = bias[col];
#pragma unroll
    for (int mi = 0; mi < 8; ++mi) {
#pragma unroll
      for (int r = 0; r < 4; ++r) {
        const size_t row = bm + wm * 128 + mi * 16 + lg * 4 + r;
        const float v = acc[mi][ni][r] + bv;
        if (OUT_BF16)
          ((bf16*)C)[row * N + col] = __float2bfloat16(v);
        else
          ((float*)C)[row * N + col] = v;
      }
    }
  }
}

// ---------------- RoPE on Q: [b][t][h*128+d] -> [b][h][t][d] ----------------
__global__ __launch_bounds__(256) void k_rope_q(
    const uint32_t* __restrict__ qin, const float* __restrict__ fc,
    const float* __restrict__ fs, uint32_t* __restrict__ qout) {
  const int tid = blockIdx.x * 256 + threadIdx.x;  // 2*2048*32*64 pairs
  const int i = tid & 63;
  const int h = (tid >> 6) & 31;
  const int t = (tid >> 11) & 2047;
  const int b = tid >> 22;
  const uint32_t u = qin[tid];
  const float t0 = bf2f((uint16_t)(u & 0xffff));
  const float t1 = bf2f((uint16_t)(u >> 16));
  const float c = fc[t * 64 + i];
  const float s = fs[t * 64 + i];
  const float r0 = t0 * c - t1 * s;
  const float r1 = t0 * s + t1 * c;
  const uint32_t o = ((uint32_t)f2bf(r1) << 16) | f2bf(r0);
  qout[(((size_t)(b * 32 + h)) * 2048 + t) * 64 + i] = o;
}

// ---------------- RoPE on K part of KV: kv[b][t][kvh*128+d] -> [b][kvh][t][d]
__global__ __launch_bounds__(256) void k_rope_k(
    const uint32_t* __restrict__ kvin, const float* __restrict__ fc,
    const float* __restrict__ fs, uint32_t* __restrict__ kout) {
  const int tid = blockIdx.x * 256 + threadIdx.x;  // 2*2048*8*64 pairs
  const int i = tid & 63;
  const int kvh = (tid >> 6) & 7;
  const int t = (tid >> 9) & 2047;
  const int b = tid >> 20;
  const uint32_t u = kvin[((size_t)(b * 2048 + t)) * 1024 + kvh * 64 + i];
  const float t0 = bf2f((uint16_t)(u & 0xffff));
  const float t1 = bf2f((uint16_t)(u >> 16));
  const float c = fc[t * 64 + i];
  const float s = fs[t * 64 + i];
  const float r0 = t0 * c - t1 * s;
  const float r1 = t0 * s + t1 * c;
  const uint32_t o = ((uint32_t)f2bf(r1) << 16) | f2bf(r0);
  kout[(((size_t)(b * 8 + kvh)) * 2048 + t) * 64 + i] = o;
}

// ---------------- V transpose: kv v-part [b][t][1024+kvh*128+d] -> [b][kvh][d][t]
__global__ __launch_bounds__(256) void k_vt(const bf16* __restrict__ kv,
                                            bf16* __restrict__ vt) {
  __shared__ __align__(16) bf16 tile[64][130];
  const int bh = blockIdx.y;  // b*8+kvh
  const int b = bh >> 3, kvh = bh & 7;
  const int t0 = blockIdx.x * 64;
  const int tid = threadIdx.x;
  const int d0 = (tid & 15) * 8;
  const int tr = tid >> 4;
#pragma unroll
  for (int j = 0; j < 4; ++j) {
    const int trow = tr + j * 16;
    const bf16* src =
        kv + ((size_t)(b * 2048) + t0 + trow) * 2048 + 1024 + kvh * 128 + d0;
    uint4 v = *(const uint4*)src;
    uint32_t* dst = (uint32_t*)&tile[trow][d0];
    dst[0] = v.x; dst[1] = v.y; dst[2] = v.z; dst[3] = v.w;
  }
  __syncthreads();
  const int d = tid >> 1;
  const int th = (tid & 1) * 32;
  uint4* out = (uint4*)(vt + (((size_t)bh) * 128 + d) * 2048 + t0 + th);
  union { bf16 h; uint16_t u; } cv;
#pragma unroll
  for (int j = 0; j < 4; ++j) {
    uint32_t wds[4];
#pragma unroll
    for (int p = 0; p < 4; ++p) {
      cv.h = tile[th + j * 8 + p * 2][d];
      uint32_t lo = cv.u;
      cv.h = tile[th + j * 8 + p * 2 + 1][d];
      wds[p] = lo | ((uint32_t)cv.u << 16);
    }
    uint4 val; val.x = wds[0]; val.y = wds[1]; val.z = wds[2]; val.w = wds[3];
    out[j] = val;
  }
}

// ---------------- causal GQA flash attention ----------------
// 1D grid of 2048 blocks, heavy-first: qi = 31 - n/64 so the 32-tile blocks
// dispatch first and light blocks backfill (load balancing).
__global__ __launch_bounds__(256) void k_attn(
    const bf16* __restrict__ Q, const bf16* __restrict__ Kr,
    const bf16* __restrict__ Vt, bf16* __restrict__ Y) {
  constexpr int T = 2048;
  __shared__ __align__(16) bf16 Ks[64 * 128];   // [key][d], XOR-swizzled rows (256B)
  __shared__ __align__(16) bf16 Vts[128 * 64];  // [d][key], XOR-swizzled rows (128B)
  __shared__ __align__(16) bf16 Ps[4][16 * 64]; // per-wave P, swizzled rows (128B)

  const int tid = threadIdx.x;
  const int lane = tid & 63;
  const int w = tid >> 6;
  const int lm = lane & 15;
  const int lg = lane >> 4;
  const int n = blockIdx.x;
  const int qi = 31 - (n >> 6);  // heavy-first
  const int hi = n & 63;
  const int b = hi >> 5;
  const int h = hi & 31;
  const int kvh = h >> 2;
  const int q0 = qi * 64;
  const int qw = q0 + w * 16;

  const bf16* qbase = Q + (((size_t)(b * 32 + h)) * T + qw) * 128;
  bf16x8 qf[4];
#pragma unroll
  for (int c = 0; c < 4; ++c)
    qf[c] = *(const bf16x8*)(qbase + lm * 128 + c * 32 + lg * 8);

  f32x4 oacc[8];
#pragma unroll
  for (int i = 0; i < 8; ++i) oacc[i] = (f32x4){0.f, 0.f, 0.f, 0.f};
  float mrow[4] = {-1e30f, -1e30f, -1e30f, -1e30f};
  float lrow[4] = {0.f, 0.f, 0.f, 0.f};

  const char* kg = (const char*)(Kr + ((size_t)(b * 8 + kvh)) * T * 128);
  const char* vg = (const char*)(Vt + ((size_t)(b * 8 + kvh)) * 128 * T);

  const int ntiles = qi + 1;
  for (int it = 0; it < ntiles; ++it) {
    const int kt = it * 64;
    __syncthreads();
#pragma unroll
    for (int i = 0; i < 4; ++i) {
      const int o = i * 4096 + w * 1024 + lane * 16;
      {
        const int row = o >> 8;
        const int cb = (o & 255) ^ ((row & 7) << 4);  // pre-swizzle source
        gld16((char*)Ks + o, kg + ((size_t)(kt + row) * 128) * 2 + cb);
      }
      {
        const int row = o >> 7;
        const int cb = (o & 127) ^ ((row & 7) << 4);
        gld16((char*)Vts + o, vg + ((size_t)row * T + kt) * 2 + cb);
      }
    }
    __syncthreads();

    // S = Q K^T (4 key sub-tiles of 16)
    f32x4 sf[4];
#pragma unroll
    for (int s = 0; s < 4; ++s) {
      f32x4 a = (f32x4){0.f, 0.f, 0.f, 0.f};
      const int key = s * 16 + lm;
#pragma unroll
      for (int c = 0; c < 4; ++c) {
        int byte = key * 256 + c * 64 + lg * 16;
        byte ^= (key & 7) << 4;
        bf16x8 kf = *(const bf16x8*)((const char*)Ks + byte);
        a = __builtin_amdgcn_mfma_f32_16x16x32_bf16(qf[c], kf, a, 0, 0, 0);
      }
      sf[s] = a;
    }

    const float scale = 0.08838834764831845f;
    float tmax[4] = {-1e30f, -1e30f, -1e30f, -1e30f};
#pragma unroll
    for (int s = 0; s < 4; ++s) {
      const int key = kt + s * 16 + lm;
#pragma unroll
      for (int r = 0; r < 4; ++r) {
        const int qrow = qw + lg * 4 + r;
        float v = sf[s][r] * scale;
        v = (key <= qrow) ? v : -1e30f;
        sf[s][r] = v;
        tmax[r] = fmaxf(tmax[r], v);
      }
    }
    float alpha[4];
#pragma unroll
    for (int r = 0; r < 4; ++r) {
      const float tm = redmax16(tmax[r]);
      const float mn = fmaxf(mrow[r], tm);
      alpha[r] = __expf(mrow[r] - mn);
      mrow[r] = mn;
    }
    float psum[4] = {0.f, 0.f, 0.f, 0.f};
#pragma unroll
    for (int s = 0; s < 4; ++s) {
#pragma unroll
      for (int r = 0; r < 4; ++r) {
        const float p = __expf(sf[s][r] - mrow[r]);
        psum[r] += p;
        const int prow = lg * 4 + r;
        int byte = prow * 128 + (s * 16 + lm) * 2;
        byte ^= (prow & 7) << 4;
        *(uint16_t*)((char*)Ps[w] + byte) = f2bf(p);
      }
    }
#pragma unroll
    for (int r = 0; r < 4; ++r) {
      lrow[r] = lrow[r] * alpha[r] + redsum16(psum[r]);
#pragma unroll
      for (int i = 0; i < 8; ++i) oacc[i][r] *= alpha[r];
    }

    // O += P V  (A-frags from per-wave Ps, B-frags from Vts)
    bf16x8 pf[2];
#pragma unroll
    for (int ks = 0; ks < 2; ++ks) {
      int byte = lm * 128 + (ks * 32 + lg * 8) * 2;
      byte ^= (lm & 7) << 4;
      pf[ks] = *(const bf16x8*)((const char*)Ps[w] + byte);
    }
#pragma unroll
    for (int dd = 0; dd < 8; ++dd) {
#pragma unroll
      for (int ks = 0; ks < 2; ++ks) {
        const int vrow = dd * 16 + lm;
        int byte = vrow * 128 + (ks * 32 + lg * 8) * 2;
        byte ^= (vrow & 7) << 4;
        bf16x8 vf = *(const bf16x8*)((const char*)Vts + byte);
        oacc[dd] = __builtin_amdgcn_mfma_f32_16x16x32_bf16(pf[ks], vf, oacc[dd], 0, 0, 0);
      }
    }
  }

#pragma unroll
  for (int r = 0; r < 4; ++r) {
    const float inv = 1.0f / lrow[r];
    const int t = qw + lg * 4 + r;
    bf16* yb = Y + ((size_t)(b * T + t)) * 4096 + h * 128;
#pragma unroll
    for (int dd = 0; dd < 8; ++dd)
      yb[dd * 16 + lm] = __float2bfloat16(oacc[dd][r] * inv);
  }
}

// ---------------- launch ----------------
extern "C" void kernel_launch(void* const* d_in, const int* in_sizes, int n_in,
                              void* d_out, int out_size, void* d_ws, size_t ws_size,
                              hipStream_t stream) {
  const float* x = (const float*)d_in[0];
  const float* fcos = (const float*)d_in[1];
  const float* fsin = (const float*)d_in[2];
  const float* wq = (const float*)d_in[3];
  const float* bq = (const float*)d_in[4];
  const float* wkv = (const float*)d_in[5];
  const float* bkv = (const float*)d_in[6];
  const float* wp = (const float*)d_in[7];
  const float* bp = (const float*)d_in[8];

  char* ws = (char*)d_ws;
  size_t off = 0;
  auto alloc = [&](size_t bytes) {
    char* p = ws + off;
    off += (bytes + 255) & ~(size_t)255;
    return p;
  };
  bf16* xb = (bf16*)alloc(16777216ull * 2);    // x bf16 [b][t][4096]
  bf16* wqb = (bf16*)alloc(16777216ull * 2);   // w_q bf16 [4096][4096]
  bf16* wkvb = (bf16*)alloc(8388608ull * 2);   // w_kv bf16 [2048][4096]
  bf16* wpb = (bf16*)alloc(16777216ull * 2);   // proj bf16 [4096][4096]
  bf16* qb = (bf16*)alloc(16777216ull * 2);    // q pre-rope [b][t][4096]; reused as Y
  bf16* kvb = (bf16*)alloc(8388608ull * 2);    // kv pre-rope [b][t][2048]
  bf16* qr = (bf16*)alloc(16777216ull * 2);    // roped Q [b][h][t][128]
  bf16* kr = (bf16*)alloc(4194304ull * 2);     // roped K [b][kvh][t][128]
  bf16* vt = (bf16*)alloc(4194304ull * 2);     // V^T [b][kvh][128][t]
  bf16* yb = qb;                               // attn out [b][t][4096] (aliases qb)

  k_cast<<<16384, 256, 0, stream>>>((const float4*)x, (uint2*)xb, 4194304);
  k_cast<<<16384, 256, 0, stream>>>((const float4*)wq, (uint2*)wqb, 4194304);
  k_cast<<<8192, 256, 0, stream>>>((const float4*)wkv, (uint2*)wkvb, 2097152);
  k_cast<<<16384, 256, 0, stream>>>((const float4*)wp, (uint2*)wpb, 4194304);

  k_gemm256<1><<<256, 512, 0, stream>>>(xb, wqb, bq, qb, 4096, 4096, 4096, 16);
  k_gemm256<1><<<128, 512, 0, stream>>>(xb, wkvb, bkv, kvb, 4096, 2048, 4096, 8);

  k_rope_q<<<32768, 256, 0, stream>>>((const uint32_t*)qb, fcos, fsin, (uint32_t*)qr);
  k_rope_k<<<8192, 256, 0, stream>>>((const uint32_t*)kvb, fcos, fsin, (uint32_t*)kr);
  k_vt<<<dim3(32, 16), 256, 0, stream>>>(kvb, vt);

  k_attn<<<2048, 256, 0, stream>>>(qr, kr, vt, yb);

  k_gemm256<0><<<256, 512, 0, stream>>>(yb, wpb, bp, d_out, 4096, 4096, 4096, 16);
}

// Round 7
// 596.035 us; speedup vs baseline: 1.5684x; 1.1006x over previous
//
#include <hip/hip_runtime.h>
#include <hip/hip_bf16.h>
#include <stdint.h>

typedef __hip_bfloat16 bf16;
typedef __attribute__((ext_vector_type(8))) __bf16 bf16x8;
typedef __attribute__((ext_vector_type(4))) float f32x4;
typedef __attribute__((ext_vector_type(16))) float f32x16;

__device__ __forceinline__ void gld16(void* lds, const void* g) {
  __builtin_amdgcn_global_load_lds(
      (const __attribute__((address_space(1))) void*)(uintptr_t)(g),
      (__attribute__((address_space(3))) void*)(uint32_t)(uintptr_t)(lds),
      16, 0, 0);
}

__device__ __forceinline__ uint16_t f2bf(float f) {
  union { bf16 h; uint16_t u; } x; x.h = __float2bfloat16(f); return x.u;
}
__device__ __forceinline__ float bf2f(uint16_t v) {
  union { uint32_t u; float f; } x; x.u = ((uint32_t)v) << 16; return x.f;
}
__device__ __forceinline__ uint32_t pk2(float lo, float hi) {
  uint32_t r;
  asm("v_cvt_pk_bf16_f32 %0, %1, %2" : "=v"(r) : "v"(lo), "v"(hi));
  return r;
}

// ---------------- f32 -> bf16 cast (vectorized) ----------------
__global__ __launch_bounds__(256) void k_cast(const float4* __restrict__ in,
                                              uint2* __restrict__ out, int n4) {
  int i = blockIdx.x * 256 + threadIdx.x;
  if (i >= n4) return;
  float4 v = in[i];
  uint32_t a = ((uint32_t)f2bf(v.y) << 16) | f2bf(v.x);
  uint32_t b = ((uint32_t)f2bf(v.w) << 16) | f2bf(v.z);
  out[i] = make_uint2(a, b);
}

// ---------------- 256x256 8-phase NT GEMM (round-4 verified form) ----------
template <int OUT_BF16>
__global__ __launch_bounds__(512, 2) void k_gemm256(
    const bf16* __restrict__ A, const bf16* __restrict__ B,
    const float* __restrict__ bias, void* __restrict__ C,
    int M, int N, int K, int gx) {
  __shared__ __align__(16) char lds[131072];  // [2 slots][A 32KB | B 32KB]
  const int tid = threadIdx.x;
  const int lane = tid & 63;
  const int w = tid >> 6;
  const int wm = w >> 2;
  const int wn = w & 3;
  const int lm = lane & 15;
  const int lg = lane >> 4;

  const int nwg = gridDim.x;
  const int cpx = nwg >> 3;
  const int bid0 = blockIdx.x;
  const int bid = (bid0 & 7) * cpx + (bid0 >> 3);
  const int bx = bid % gx;
  const int by = bid / gx;
  const size_t bm = (size_t)by * 256;
  const size_t bn = (size_t)bx * 256;

  const int srow = tid >> 3;
  const int scb = ((tid & 7) * 16) ^ ((srow & 7) << 4);
  const char* asrc[4];
  const char* bsrc[4];
#pragma unroll
  for (int j = 0; j < 4; ++j) {
    asrc[j] = (const char*)(A + (bm + j * 64 + srow) * K) + scb;
    bsrc[j] = (const char*)(B + (bn + j * 64 + srow) * K) + scb;
  }
  const int ldst = tid * 16;

  const int colb0 = (lg * 16) ^ ((lm & 7) << 4);
  const int colb1 = colb0 ^ 64;

  f32x4 acc[8][4];
#pragma unroll
  for (int i = 0; i < 8; ++i)
#pragma unroll
    for (int j = 0; j < 4; ++j) acc[i][j] = (f32x4){0.f, 0.f, 0.f, 0.f};

  const int NT = K >> 6;

  {
    char* la = lds;
    char* lb = lds + 32768;
#pragma unroll
    for (int j = 0; j < 4; ++j) {
      gld16(la + j * 8192 + ldst, asrc[j]);
      gld16(lb + j * 8192 + ldst, bsrc[j]);
    }
  }

  for (int t = 0; t < NT; ++t) {
    const int slot = t & 1;
    if (t + 1 < NT) {
      char* la = lds + (slot ^ 1) * 65536;
      char* lb = la + 32768;
      const size_t ko = (size_t)(t + 1) * 128;
#pragma unroll
      for (int j = 0; j < 4; ++j) {
        gld16(la + j * 8192 + ldst, asrc[j] + ko);
        gld16(lb + j * 8192 + ldst, bsrc[j] + ko);
      }
      asm volatile("s_waitcnt vmcnt(8)" ::: "memory");
    } else {
      asm volatile("s_waitcnt vmcnt(0)" ::: "memory");
    }
    __builtin_amdgcn_s_barrier();

    const char* la = lds + slot * 65536;
    const char* lb = la + 32768;
    bf16x8 bfrag[4][2];

#pragma unroll
    for (int p = 0; p < 4; ++p) {
      if (p == 0) {
#pragma unroll
        for (int ni = 0; ni < 4; ++ni) {
          const int br = wn * 64 + ni * 16 + lm;
          bfrag[ni][0] = *(const bf16x8*)(lb + br * 128 + colb0);
          bfrag[ni][1] = *(const bf16x8*)(lb + br * 128 + colb1);
        }
      }
      bf16x8 af[2][2];
#pragma unroll
      for (int q = 0; q < 2; ++q) {
        const int ar = wm * 128 + (2 * p + q) * 16 + lm;
        af[q][0] = *(const bf16x8*)(la + ar * 128 + colb0);
        af[q][1] = *(const bf16x8*)(la + ar * 128 + colb1);
      }
      __builtin_amdgcn_s_barrier();
      asm volatile("s_waitcnt lgkmcnt(0)" ::: "memory");
      __builtin_amdgcn_sched_barrier(0);
      __builtin_amdgcn_s_setprio(1);
#pragma unroll
      for (int q = 0; q < 2; ++q)
#pragma unroll
        for (int ni = 0; ni < 4; ++ni) {
          acc[2 * p + q][ni] = __builtin_amdgcn_mfma_f32_16x16x32_bf16(
              af[q][0], bfrag[ni][0], acc[2 * p + q][ni], 0, 0, 0);
          acc[2 * p + q][ni] = __builtin_amdgcn_mfma_f32_16x16x32_bf16(
              af[q][1], bfrag[ni][1], acc[2 * p + q][ni], 0, 0, 0);
        }
      __builtin_amdgcn_s_setprio(0);
      __builtin_amdgcn_s_barrier();
    }
  }

#pragma unroll
  for (int ni = 0; ni < 4; ++ni) {
    const size_t col = bn + wn * 64 + ni * 16 + lm;
    const float bv = bias[col];
#pragma unroll
    for (int mi = 0; mi < 8; ++mi) {
#pragma unroll
      for (int r = 0; r < 4; ++r) {
        const size_t row = bm + wm * 128 + mi * 16 + lg * 4 + r;
        const float v = acc[mi][ni][r] + bv;
        if (OUT_BF16)
          ((bf16*)C)[row * N + col] = __float2bfloat16(v);
        else
          ((float*)C)[row * N + col] = v;
      }
    }
  }
}

// ---------------- RoPE on Q: [b][t][h*128+d] -> [b][h][t][d] ----------------
__global__ __launch_bounds__(256) void k_rope_q(
    const uint32_t* __restrict__ qin, const float* __restrict__ fc,
    const float* __restrict__ fs, uint32_t* __restrict__ qout) {
  const int tid = blockIdx.x * 256 + threadIdx.x;
  const int i = tid & 63;
  const int h = (tid >> 6) & 31;
  const int t = (tid >> 11) & 2047;
  const int b = tid >> 22;
  const uint32_t u = qin[tid];
  const float t0 = bf2f((uint16_t)(u & 0xffff));
  const float t1 = bf2f((uint16_t)(u >> 16));
  const float c = fc[t * 64 + i];
  const float s = fs[t * 64 + i];
  const float r0 = t0 * c - t1 * s;
  const float r1 = t0 * s + t1 * c;
  const uint32_t o = ((uint32_t)f2bf(r1) << 16) | f2bf(r0);
  qout[(((size_t)(b * 32 + h)) * 2048 + t) * 64 + i] = o;
}

// ---------------- RoPE on K part of KV ----------------
__global__ __launch_bounds__(256) void k_rope_k(
    const uint32_t* __restrict__ kvin, const float* __restrict__ fc,
    const float* __restrict__ fs, uint32_t* __restrict__ kout) {
  const int tid = blockIdx.x * 256 + threadIdx.x;
  const int i = tid & 63;
  const int kvh = (tid >> 6) & 7;
  const int t = (tid >> 9) & 2047;
  const int b = tid >> 20;
  const uint32_t u = kvin[((size_t)(b * 2048 + t)) * 1024 + kvh * 64 + i];
  const float t0 = bf2f((uint16_t)(u & 0xffff));
  const float t1 = bf2f((uint16_t)(u >> 16));
  const float c = fc[t * 64 + i];
  const float s = fs[t * 64 + i];
  const float r0 = t0 * c - t1 * s;
  const float r1 = t0 * s + t1 * c;
  const uint32_t o = ((uint32_t)f2bf(r1) << 16) | f2bf(r0);
  kout[(((size_t)(b * 8 + kvh)) * 2048 + t) * 64 + i] = o;
}

// ---------------- V transpose -> [b][kvh][d][t] ----------------
__global__ __launch_bounds__(256) void k_vt(const bf16* __restrict__ kv,
                                            bf16* __restrict__ vt) {
  __shared__ __align__(16) bf16 tile[64][130];
  const int bh = blockIdx.y;
  const int b = bh >> 3, kvh = bh & 7;
  const int t0 = blockIdx.x * 64;
  const int tid = threadIdx.x;
  const int d0 = (tid & 15) * 8;
  const int tr = tid >> 4;
#pragma unroll
  for (int j = 0; j < 4; ++j) {
    const int trow = tr + j * 16;
    const bf16* src =
        kv + ((size_t)(b * 2048) + t0 + trow) * 2048 + 1024 + kvh * 128 + d0;
    uint4 v = *(const uint4*)src;
    uint32_t* dst = (uint32_t*)&tile[trow][d0];
    dst[0] = v.x; dst[1] = v.y; dst[2] = v.z; dst[3] = v.w;
  }
  __syncthreads();
  const int d = tid >> 1;
  const int th = (tid & 1) * 32;
  uint4* out = (uint4*)(vt + (((size_t)bh) * 128 + d) * 2048 + t0 + th);
  union { bf16 h; uint16_t u; } cv;
#pragma unroll
  for (int j = 0; j < 4; ++j) {
    uint32_t wds[4];
#pragma unroll
    for (int p = 0; p < 4; ++p) {
      cv.h = tile[th + j * 8 + p * 2][d];
      uint32_t lo = cv.u;
      cv.h = tile[th + j * 8 + p * 2 + 1][d];
      wds[p] = lo | ((uint32_t)cv.u << 16);
    }
    uint4 val; val.x = wds[0]; val.y = wds[1]; val.z = wds[2]; val.w = wds[3];
    out[j] = val;
  }
}

// ---------------- causal GQA flash attention, 8-warp 32x32 swapped-QK^T ----
// SAFE-SYNC variant: plain __syncthreads() (full vmcnt/lgkm drain + barrier)
// around every LDS producer/consumer boundary; stage-next issued between the
// two fences so HBM latency still overlaps compute. Unconditional rescale.
__global__ __launch_bounds__(512) void k_attn(
    const bf16* __restrict__ Q, const bf16* __restrict__ Kr,
    const bf16* __restrict__ Vt, bf16* __restrict__ Y) {
  constexpr int T = 2048;
  __shared__ __align__(16) char lds[65536];  // [2][K 16KB | V 16KB]
  const int tid = threadIdx.x;
  const int lane = tid & 63;
  const int w = tid >> 6;
  const int l31 = lane & 31;
  const int hi = lane >> 5;

  const int n = blockIdx.x;
  const int qc = 7 - (n >> 6);  // heavy-first
  const int bh = n & 63;
  const int b = bh >> 5, h = bh & 31, kvh = h >> 2;

  const int qrow = qc * 256 + w * 32 + l31;
  const int qmaxw = qc * 256 + w * 32 + 31;
  const int NT = qc * 4 + 4;

  const bf16* qptr = Q + (((size_t)(b * 32 + h)) * T + qrow) * 128 + hi * 8;
  bf16x8 qf[8];
#pragma unroll
  for (int kt = 0; kt < 8; ++kt) qf[kt] = *(const bf16x8*)(qptr + kt * 16);

  const char* kg = (const char*)(Kr + ((size_t)(b * 8 + kvh)) * T * 128);
  const char* vg = (const char*)(Vt + ((size_t)(b * 8 + kvh)) * 128 * T);
  const char* ksrc[2];
  const char* vsrc[2];
  int kdst[2], vdst[2];
#pragma unroll
  for (int j = 0; j < 2; ++j) {
    const int o = j * 8192 + tid * 16;
    const int krow = o >> 8, kin = o & 255;
    ksrc[j] = kg + (size_t)krow * 256 + (kin ^ ((krow & 15) << 4));
    kdst[j] = o;
    const int vrow = o >> 7, vin = o & 127;
    vsrc[j] = vg + (size_t)vrow * (T * 2) + (vin ^ ((vrow & 7) << 4));
    vdst[j] = 16384 + o;
  }

  f32x16 oacc[4];
#pragma unroll
  for (int d = 0; d < 4; ++d)
#pragma unroll
    for (int r = 0; r < 16; ++r) oacc[d][r] = 0.f;
  float m = -1e30f, l = 0.f;
  const float c1 = 0.08838834764831845f * 1.44269504089f;  // scale*log2e

  // prologue: stage tile 0 -> buf 0
#pragma unroll
  for (int j = 0; j < 2; ++j) {
    gld16(lds + kdst[j], ksrc[j]);
    gld16(lds + vdst[j], vsrc[j]);
  }

  for (int it = 0; it < NT; ++it) {
    const int buf = it & 1;
    __syncthreads();  // drains all vmcnt (tile-it staging) + block barrier

    if (it + 1 < NT) {  // stage next tile into the other buffer (overlaps)
      const int nb = buf ^ 1;
      const size_t ko = (size_t)(it + 1) * 16384;
      const size_t vo = (size_t)(it + 1) * 128;
#pragma unroll
      for (int j = 0; j < 2; ++j) {
        gld16(lds + nb * 32768 + kdst[j], ksrc[j] + ko);
        gld16(lds + nb * 32768 + vdst[j], vsrc[j] + vo);
      }
    }

    const int kt0 = it * 64;
    if (kt0 <= qmaxw) {  // warp-uniform: skip fully-masked tiles
      const char* kb = lds + buf * 32768;
      const char* vb = kb + 16384;

      // S^T = K Q^T  (two 32-key subtiles)
      f32x16 s0, s1;
#pragma unroll
      for (int r = 0; r < 16; ++r) { s0[r] = 0.f; s1[r] = 0.f; }
      const int kswz = (l31 & 15) << 4;
#pragma unroll
      for (int kt = 0; kt < 8; ++kt) {
        const int cb = (kt * 32 + hi * 16) ^ kswz;
        bf16x8 kf0 = *(const bf16x8*)(kb + l31 * 256 + cb);
        bf16x8 kf1 = *(const bf16x8*)(kb + (32 + l31) * 256 + cb);
        s0 = __builtin_amdgcn_mfma_f32_32x32x16_bf16(kf0, qf[kt], s0, 0, 0, 0);
        s1 = __builtin_amdgcn_mfma_f32_32x32x16_bf16(kf1, qf[kt], s1, 0, 0, 0);
      }

      // mask + scale (log2 units) + row max
      float tmax = -1e30f;
#pragma unroll
      for (int r = 0; r < 16; ++r) {
        const int key0 = kt0 + (r & 3) + 8 * (r >> 2) + 4 * hi;
        float v0 = s0[r] * c1;
        v0 = (key0 <= qrow) ? v0 : -1e30f;
        s0[r] = v0; tmax = fmaxf(tmax, v0);
        float v1 = s1[r] * c1;
        v1 = (key0 + 32 <= qrow) ? v1 : -1e30f;
        s1[r] = v1; tmax = fmaxf(tmax, v1);
      }
      tmax = fmaxf(tmax, __shfl_xor(tmax, 32));

      // online update, unconditional rescale
      const float mn = fmaxf(m, tmax);
      const float alpha = __builtin_amdgcn_exp2f(m - mn);
      m = mn;
      l *= alpha;
      float aw[16];
#pragma unroll
      for (int g = 0; g < 4; ++g)
#pragma unroll
        for (int c = 0; c < 4; ++c)
          aw[g * 4 + c] = __shfl(alpha, g * 8 + hi * 4 + c, 64);
#pragma unroll
      for (int r = 0; r < 16; ++r) {
        const float a2 = aw[(r >> 2) * 4 + (r & 3)];
        oacc[0][r] *= a2; oacc[1][r] *= a2;
        oacc[2][r] *= a2; oacc[3][r] *= a2;
      }

      // P = exp2(s - m), row sum
      float ls = 0.f;
#pragma unroll
      for (int r = 0; r < 16; ++r) {
        const float p0 = __builtin_amdgcn_exp2f(s0[r] - m); s0[r] = p0; ls += p0;
        const float p1 = __builtin_amdgcn_exp2f(s1[r] - m); s1[r] = p1; ls += p1;
      }
      l += ls + __shfl_xor(ls, 32);

      // PV: 4 k-steps of 16 keys; A-words via cvt_pk + lane^32 exchange
#pragma unroll
      for (int t = 0; t < 4; ++t) {
        uint32_t a0, a1, b0, b1;
        if (t == 0) {
          a0 = pk2(s0[0], s0[1]); a1 = pk2(s0[2], s0[3]);
          b0 = pk2(s0[4], s0[5]); b1 = pk2(s0[6], s0[7]);
        } else if (t == 1) {
          a0 = pk2(s0[8], s0[9]); a1 = pk2(s0[10], s0[11]);
          b0 = pk2(s0[12], s0[13]); b1 = pk2(s0[14], s0[15]);
        } else if (t == 2) {
          a0 = pk2(s1[0], s1[1]); a1 = pk2(s1[2], s1[3]);
          b0 = pk2(s1[4], s1[5]); b1 = pk2(s1[6], s1[7]);
        } else {
          a0 = pk2(s1[8], s1[9]); a1 = pk2(s1[10], s1[11]);
          b0 = pk2(s1[12], s1[13]); b1 = pk2(s1[14], s1[15]);
        }
        const uint32_t sa0 = __shfl_xor(a0, 32), sa1 = __shfl_xor(a1, 32);
        const uint32_t sb0 = __shfl_xor(b0, 32), sb1 = __shfl_xor(b1, 32);
        union { uint32_t u[4]; bf16x8 v; } A;
        A.u[0] = hi ? sb0 : a0;
        A.u[1] = hi ? sb1 : a1;
        A.u[2] = hi ? b0 : sa0;
        A.u[3] = hi ? b1 : sa1;
#pragma unroll
        for (int d = 0; d < 4; ++d) {
          const int vrow = d * 32 + l31;
          const int vcb = (32 * t + 16 * hi) ^ ((vrow & 7) << 4);
          bf16x8 vf = *(const bf16x8*)(vb + vrow * 128 + vcb);
          oacc[d] = __builtin_amdgcn_mfma_f32_32x32x16_bf16(A.v, vf, oacc[d], 0, 0, 0);
        }
      }
    }
    __syncthreads();  // all reads of buf done before it is overwritten
  }

  // epilogue: 1/l redistribution + store
  const float linv = 1.0f / l;
  float lw[16];
#pragma unroll
  for (int g = 0; g < 4; ++g)
#pragma unroll
    for (int c = 0; c < 4; ++c)
      lw[g * 4 + c] = __shfl(linv, g * 8 + hi * 4 + c, 64);
  bf16* yb = Y + ((size_t)b * T) * 4096 + h * 128 + l31;
#pragma unroll
  for (int d = 0; d < 4; ++d)
#pragma unroll
    for (int r = 0; r < 16; ++r) {
      const int qp = (r & 3) + 8 * (r >> 2) + 4 * hi;
      const size_t trow = qc * 256 + w * 32 + qp;
      yb[trow * 4096 + d * 32] =
          __float2bfloat16(oacc[d][r] * lw[(r >> 2) * 4 + (r & 3)]);
    }
}

// ---------------- launch ----------------
extern "C" void kernel_launch(void* const* d_in, const int* in_sizes, int n_in,
                              void* d_out, int out_size, void* d_ws, size_t ws_size,
                              hipStream_t stream) {
  const float* x = (const float*)d_in[0];
  const float* fcos = (const float*)d_in[1];
  const float* fsin = (const float*)d_in[2];
  const float* wq = (const float*)d_in[3];
  const float* bq = (const float*)d_in[4];
  const float* wkv = (const float*)d_in[5];
  const float* bkv = (const float*)d_in[6];
  const float* wp = (const float*)d_in[7];
  const float* bp = (const float*)d_in[8];

  char* ws = (char*)d_ws;
  size_t off = 0;
  auto alloc = [&](size_t bytes) {
    char* p = ws + off;
    off += (bytes + 255) & ~(size_t)255;
    return p;
  };
  bf16* xb = (bf16*)alloc(16777216ull * 2);
  bf16* wqb = (bf16*)alloc(16777216ull * 2);
  bf16* wkvb = (bf16*)alloc(8388608ull * 2);
  bf16* wpb = (bf16*)alloc(16777216ull * 2);
  bf16* qb = (bf16*)alloc(16777216ull * 2);
  bf16* kvb = (bf16*)alloc(8388608ull * 2);
  bf16* qr = (bf16*)alloc(16777216ull * 2);
  bf16* kr = (bf16*)alloc(4194304ull * 2);
  bf16* vt = (bf16*)alloc(4194304ull * 2);
  bf16* yb = qb;

  k_cast<<<16384, 256, 0, stream>>>((const float4*)x, (uint2*)xb, 4194304);
  k_cast<<<16384, 256, 0, stream>>>((const float4*)wq, (uint2*)wqb, 4194304);
  k_cast<<<8192, 256, 0, stream>>>((const float4*)wkv, (uint2*)wkvb, 2097152);
  k_cast<<<16384, 256, 0, stream>>>((const float4*)wp, (uint2*)wpb, 4194304);

  k_gemm256<1><<<256, 512, 0, stream>>>(xb, wqb, bq, qb, 4096, 4096, 4096, 16);
  k_gemm256<1><<<128, 512, 0, stream>>>(xb, wkvb, bkv, kvb, 4096, 2048, 4096, 8);

  k_rope_q<<<32768, 256, 0, stream>>>((const uint32_t*)qb, fcos, fsin, (uint32_t*)qr);
  k_rope_k<<<8192, 256, 0, stream>>>((const uint32_t*)kvb, fcos, fsin, (uint32_t*)kr);
  k_vt<<<dim3(32, 16), 256, 0, stream>>>(kvb, vt);

  k_attn<<<512, 512, 0, stream>>>(qr, kr, vt, yb);

  k_gemm256<0><<<256, 512, 0, stream>>>(yb, wpb, bp, d_out, 4096, 4096, 4096, 16);
}

// Round 8
// 569.117 us; speedup vs baseline: 1.6426x; 1.0473x over previous
//
#include <hip/hip_runtime.h>
#include <hip/hip_bf16.h>
#include <stdint.h>

typedef __hip_bfloat16 bf16;
typedef __attribute__((ext_vector_type(8))) __bf16 bf16x8;
typedef __attribute__((ext_vector_type(4))) float f32x4;
typedef __attribute__((ext_vector_type(16))) float f32x16;

__device__ __forceinline__ void gld16(void* lds, const void* g) {
  __builtin_amdgcn_global_load_lds(
      (const __attribute__((address_space(1))) void*)(uintptr_t)(g),
      (__attribute__((address_space(3))) void*)(uint32_t)(uintptr_t)(lds),
      16, 0, 0);
}

__device__ __forceinline__ uint16_t f2bf(float f) {
  union { bf16 h; uint16_t u; } x; x.h = __float2bfloat16(f); return x.u;
}
__device__ __forceinline__ float bf2f(uint16_t v) {
  union { uint32_t u; float f; } x; x.u = ((uint32_t)v) << 16; return x.f;
}
__device__ __forceinline__ uint32_t pk2(float lo, float hi) {
  uint32_t r;
  asm("v_cvt_pk_bf16_f32 %0, %1, %2" : "=v"(r) : "v"(lo), "v"(hi));
  return r;
}

// ---------------- f32 -> bf16 cast (vectorized) ----------------
__global__ __launch_bounds__(256) void k_cast(const float4* __restrict__ in,
                                              uint2* __restrict__ out, int n4) {
  int i = blockIdx.x * 256 + threadIdx.x;
  if (i >= n4) return;
  float4 v = in[i];
  uint32_t a = ((uint32_t)f2bf(v.y) << 16) | f2bf(v.x);
  uint32_t b = ((uint32_t)f2bf(v.w) << 16) | f2bf(v.z);
  out[i] = make_uint2(a, b);
}

// ---------------- 256x256 NT GEMM, overlap-phase K-loop ----------------
// Per K-tile: top vmcnt(8)+barrier, then 4 intervals of
// [lgkmcnt(0) -> 16 MFMA -> ds_reads for next interval] with ONE barrier per
// boundary (5 barriers/tile). A wave done with MFMAs streams next-phase LDS
// reads while sibling waves still MFMA -> LDS hides under MFMA (round-7 form
// fully alternated them: MfmaUtil 34.6%). Slot safety: staging into slot^1 is
// gated by the end-of-tile barrier; per-wave read->MFMA is a register dep.
template <int OUT_BF16>
__global__ __launch_bounds__(512, 2) void k_gemm256(
    const bf16* __restrict__ A, const bf16* __restrict__ B,
    const float* __restrict__ bias, void* __restrict__ C,
    int M, int N, int K, int gx) {
  __shared__ __align__(16) char lds[131072];  // [2 slots][A 32KB | B 32KB]
  const int tid = threadIdx.x;
  const int lane = tid & 63;
  const int w = tid >> 6;
  const int wm = w >> 2;
  const int wn = w & 3;
  const int lm = lane & 15;
  const int lg = lane >> 4;

  const int nwg = gridDim.x;
  const int cpx = nwg >> 3;
  const int bid0 = blockIdx.x;
  const int bid = (bid0 & 7) * cpx + (bid0 >> 3);
  const int bx = bid % gx;
  const int by = bid / gx;
  const size_t bm = (size_t)by * 256;
  const size_t bn = (size_t)bx * 256;

  const int srow = tid >> 3;
  const int scb = ((tid & 7) * 16) ^ ((srow & 7) << 4);
  const char* asrc[4];
  const char* bsrc[4];
#pragma unroll
  for (int j = 0; j < 4; ++j) {
    asrc[j] = (const char*)(A + (bm + j * 64 + srow) * K) + scb;
    bsrc[j] = (const char*)(B + (bn + j * 64 + srow) * K) + scb;
  }
  const int ldst = tid * 16;

  const int colb0 = (lg * 16) ^ ((lm & 7) << 4);
  const int colb1 = colb0 ^ 64;

  f32x4 acc[8][4];
#pragma unroll
  for (int i = 0; i < 8; ++i)
#pragma unroll
    for (int j = 0; j < 4; ++j) acc[i][j] = (f32x4){0.f, 0.f, 0.f, 0.f};

  const int NT = K >> 6;

  {
    char* la = lds;
    char* lb = lds + 32768;
#pragma unroll
    for (int j = 0; j < 4; ++j) {
      gld16(la + j * 8192 + ldst, asrc[j]);
      gld16(lb + j * 8192 + ldst, bsrc[j]);
    }
  }

  for (int t = 0; t < NT; ++t) {
    const int slot = t & 1;
    if (t + 1 < NT) {
      char* la = lds + (slot ^ 1) * 65536;
      char* lb = la + 32768;
      const size_t ko = (size_t)(t + 1) * 128;
#pragma unroll
      for (int j = 0; j < 4; ++j) {
        gld16(la + j * 8192 + ldst, asrc[j] + ko);
        gld16(lb + j * 8192 + ldst, bsrc[j] + ko);
      }
      asm volatile("s_waitcnt vmcnt(8)" ::: "memory");
    } else {
      asm volatile("s_waitcnt vmcnt(0)" ::: "memory");
    }
    __builtin_amdgcn_s_barrier();  // slot-t data visible to all waves

    const char* la = lds + slot * 65536;
    const char* lb = la + 32768;

    // reads for interval 0: all B-frags + A-frags (mi 0,1)
    bf16x8 bfrag[4][2];
#pragma unroll
    for (int ni = 0; ni < 4; ++ni) {
      const int br = wn * 64 + ni * 16 + lm;
      bfrag[ni][0] = *(const bf16x8*)(lb + br * 128 + colb0);
      bfrag[ni][1] = *(const bf16x8*)(lb + br * 128 + colb1);
    }
    bf16x8 af[2][2];
#pragma unroll
    for (int q = 0; q < 2; ++q) {
      const int ar = wm * 128 + q * 16 + lm;
      af[q][0] = *(const bf16x8*)(la + ar * 128 + colb0);
      af[q][1] = *(const bf16x8*)(la + ar * 128 + colb1);
    }

#pragma unroll
    for (int p = 0; p < 4; ++p) {
      asm volatile("s_waitcnt lgkmcnt(0)" ::: "memory");
      __builtin_amdgcn_sched_barrier(0);
      __builtin_amdgcn_s_setprio(1);
      bf16x8 a00 = af[0][0], a01 = af[0][1];
      bf16x8 a10 = af[1][0], a11 = af[1][1];
#pragma unroll
      for (int ni = 0; ni < 4; ++ni) {
        acc[2 * p][ni] = __builtin_amdgcn_mfma_f32_16x16x32_bf16(
            a00, bfrag[ni][0], acc[2 * p][ni], 0, 0, 0);
        acc[2 * p][ni] = __builtin_amdgcn_mfma_f32_16x16x32_bf16(
            a01, bfrag[ni][1], acc[2 * p][ni], 0, 0, 0);
        acc[2 * p + 1][ni] = __builtin_amdgcn_mfma_f32_16x16x32_bf16(
            a10, bfrag[ni][0], acc[2 * p + 1][ni], 0, 0, 0);
        acc[2 * p + 1][ni] = __builtin_amdgcn_mfma_f32_16x16x32_bf16(
            a11, bfrag[ni][1], acc[2 * p + 1][ni], 0, 0, 0);
      }
      __builtin_amdgcn_s_setprio(0);
      if (p < 3) {
        // prefetch A-frags for interval p+1 (same stable slot; overlaps with
        // sibling waves' MFMAs -- no barrier between MFMA and these reads)
#pragma unroll
        for (int q = 0; q < 2; ++q) {
          const int ar = wm * 128 + (2 * (p + 1) + q) * 16 + lm;
          af[q][0] = *(const bf16x8*)(la + ar * 128 + colb0);
          af[q][1] = *(const bf16x8*)(la + ar * 128 + colb1);
        }
        __builtin_amdgcn_s_barrier();  // interval boundary
      }
    }
    __builtin_amdgcn_s_barrier();  // end of tile: all reads of slot done
  }

#pragma unroll
  for (int ni = 0; ni < 4; ++ni) {
    const size_t col = bn + wn * 64 + ni * 16 + lm;
    const float bv = bias[col];
#pragma unroll
    for (int mi = 0; mi < 8; ++mi) {
#pragma unroll
      for (int r = 0; r < 4; ++r) {
        const size_t row = bm + wm * 128 + mi * 16 + lg * 4 + r;
        const float v = acc[mi][ni][r] + bv;
        if (OUT_BF16)
          ((bf16*)C)[row * N + col] = __float2bfloat16(v);
        else
          ((float*)C)[row * N + col] = v;
      }
    }
  }
}

// ---------------- RoPE on Q: [b][t][h*128+d] -> [b][h][t][d] ----------------
__global__ __launch_bounds__(256) void k_rope_q(
    const uint32_t* __restrict__ qin, const float* __restrict__ fc,
    const float* __restrict__ fs, uint32_t* __restrict__ qout) {
  const int tid = blockIdx.x * 256 + threadIdx.x;
  const int i = tid & 63;
  const int h = (tid >> 6) & 31;
  const int t = (tid >> 11) & 2047;
  const int b = tid >> 22;
  const uint32_t u = qin[tid];
  const float t0 = bf2f((uint16_t)(u & 0xffff));
  const float t1 = bf2f((uint16_t)(u >> 16));
  const float c = fc[t * 64 + i];
  const float s = fs[t * 64 + i];
  const float r0 = t0 * c - t1 * s;
  const float r1 = t0 * s + t1 * c;
  const uint32_t o = ((uint32_t)f2bf(r1) << 16) | f2bf(r0);
  qout[(((size_t)(b * 32 + h)) * 2048 + t) * 64 + i] = o;
}

// ---------------- RoPE on K part of KV ----------------
__global__ __launch_bounds__(256) void k_rope_k(
    const uint32_t* __restrict__ kvin, const float* __restrict__ fc,
    const float* __restrict__ fs, uint32_t* __restrict__ kout) {
  const int tid = blockIdx.x * 256 + threadIdx.x;
  const int i = tid & 63;
  const int kvh = (tid >> 6) & 7;
  const int t = (tid >> 9) & 2047;
  const int b = tid >> 20;
  const uint32_t u = kvin[((size_t)(b * 2048 + t)) * 1024 + kvh * 64 + i];
  const float t0 = bf2f((uint16_t)(u & 0xffff));
  const float t1 = bf2f((uint16_t)(u >> 16));
  const float c = fc[t * 64 + i];
  const float s = fs[t * 64 + i];
  const float r0 = t0 * c - t1 * s;
  const float r1 = t0 * s + t1 * c;
  const uint32_t o = ((uint32_t)f2bf(r1) << 16) | f2bf(r0);
  kout[(((size_t)(b * 8 + kvh)) * 2048 + t) * 64 + i] = o;
}

// ---------------- V transpose -> [b][kvh][d][t] ----------------
__global__ __launch_bounds__(256) void k_vt(const bf16* __restrict__ kv,
                                            bf16* __restrict__ vt) {
  __shared__ __align__(16) bf16 tile[64][130];
  const int bh = blockIdx.y;
  const int b = bh >> 3, kvh = bh & 7;
  const int t0 = blockIdx.x * 64;
  const int tid = threadIdx.x;
  const int d0 = (tid & 15) * 8;
  const int tr = tid >> 4;
#pragma unroll
  for (int j = 0; j < 4; ++j) {
    const int trow = tr + j * 16;
    const bf16* src =
        kv + ((size_t)(b * 2048) + t0 + trow) * 2048 + 1024 + kvh * 128 + d0;
    uint4 v = *(const uint4*)src;
    uint32_t* dst = (uint32_t*)&tile[trow][d0];
    dst[0] = v.x; dst[1] = v.y; dst[2] = v.z; dst[3] = v.w;
  }
  __syncthreads();
  const int d = tid >> 1;
  const int th = (tid & 1) * 32;
  uint4* out = (uint4*)(vt + (((size_t)bh) * 128 + d) * 2048 + t0 + th);
  union { bf16 h; uint16_t u; } cv;
#pragma unroll
  for (int j = 0; j < 4; ++j) {
    uint32_t wds[4];
#pragma unroll
    for (int p = 0; p < 4; ++p) {
      cv.h = tile[th + j * 8 + p * 2][d];
      uint32_t lo = cv.u;
      cv.h = tile[th + j * 8 + p * 2 + 1][d];
      wds[p] = lo | ((uint32_t)cv.u << 16);
    }
    uint4 val; val.x = wds[0]; val.y = wds[1]; val.z = wds[2]; val.w = wds[3];
    out[j] = val;
  }
}

// ---------------- causal GQA flash attention, 8-warp 32x32 swapped-QK^T ----
// SAFE-SYNC (round-7 verified form, unchanged).
__global__ __launch_bounds__(512) void k_attn(
    const bf16* __restrict__ Q, const bf16* __restrict__ Kr,
    const bf16* __restrict__ Vt, bf16* __restrict__ Y) {
  constexpr int T = 2048;
  __shared__ __align__(16) char lds[65536];  // [2][K 16KB | V 16KB]
  const int tid = threadIdx.x;
  const int lane = tid & 63;
  const int w = tid >> 6;
  const int l31 = lane & 31;
  const int hi = lane >> 5;

  const int n = blockIdx.x;
  const int qc = 7 - (n >> 6);  // heavy-first
  const int bh = n & 63;
  const int b = bh >> 5, h = bh & 31, kvh = h >> 2;

  const int qrow = qc * 256 + w * 32 + l31;
  const int qmaxw = qc * 256 + w * 32 + 31;
  const int NT = qc * 4 + 4;

  const bf16* qptr = Q + (((size_t)(b * 32 + h)) * T + qrow) * 128 + hi * 8;
  bf16x8 qf[8];
#pragma unroll
  for (int kt = 0; kt < 8; ++kt) qf[kt] = *(const bf16x8*)(qptr + kt * 16);

  const char* kg = (const char*)(Kr + ((size_t)(b * 8 + kvh)) * T * 128);
  const char* vg = (const char*)(Vt + ((size_t)(b * 8 + kvh)) * 128 * T);
  const char* ksrc[2];
  const char* vsrc[2];
  int kdst[2], vdst[2];
#pragma unroll
  for (int j = 0; j < 2; ++j) {
    const int o = j * 8192 + tid * 16;
    const int krow = o >> 8, kin = o & 255;
    ksrc[j] = kg + (size_t)krow * 256 + (kin ^ ((krow & 15) << 4));
    kdst[j] = o;
    const int vrow = o >> 7, vin = o & 127;
    vsrc[j] = vg + (size_t)vrow * (T * 2) + (vin ^ ((vrow & 7) << 4));
    vdst[j] = 16384 + o;
  }

  f32x16 oacc[4];
#pragma unroll
  for (int d = 0; d < 4; ++d)
#pragma unroll
    for (int r = 0; r < 16; ++r) oacc[d][r] = 0.f;
  float m = -1e30f, l = 0.f;
  const float c1 = 0.08838834764831845f * 1.44269504089f;  // scale*log2e

  // prologue: stage tile 0 -> buf 0
#pragma unroll
  for (int j = 0; j < 2; ++j) {
    gld16(lds + kdst[j], ksrc[j]);
    gld16(lds + vdst[j], vsrc[j]);
  }

  for (int it = 0; it < NT; ++it) {
    const int buf = it & 1;
    __syncthreads();  // drains all vmcnt (tile-it staging) + block barrier

    if (it + 1 < NT) {  // stage next tile into the other buffer (overlaps)
      const int nb = buf ^ 1;
      const size_t ko = (size_t)(it + 1) * 16384;
      const size_t vo = (size_t)(it + 1) * 128;
#pragma unroll
      for (int j = 0; j < 2; ++j) {
        gld16(lds + nb * 32768 + kdst[j], ksrc[j] + ko);
        gld16(lds + nb * 32768 + vdst[j], vsrc[j] + vo);
      }
    }

    const int kt0 = it * 64;
    if (kt0 <= qmaxw) {  // warp-uniform: skip fully-masked tiles
      const char* kb = lds + buf * 32768;
      const char* vb = kb + 16384;

      // S^T = K Q^T  (two 32-key subtiles)
      f32x16 s0, s1;
#pragma unroll
      for (int r = 0; r < 16; ++r) { s0[r] = 0.f; s1[r] = 0.f; }
      const int kswz = (l31 & 15) << 4;
#pragma unroll
      for (int kt = 0; kt < 8; ++kt) {
        const int cb = (kt * 32 + hi * 16) ^ kswz;
        bf16x8 kf0 = *(const bf16x8*)(kb + l31 * 256 + cb);
        bf16x8 kf1 = *(const bf16x8*)(kb + (32 + l31) * 256 + cb);
        s0 = __builtin_amdgcn_mfma_f32_32x32x16_bf16(kf0, qf[kt], s0, 0, 0, 0);
        s1 = __builtin_amdgcn_mfma_f32_32x32x16_bf16(kf1, qf[kt], s1, 0, 0, 0);
      }

      // mask + scale (log2 units) + row max
      float tmax = -1e30f;
#pragma unroll
      for (int r = 0; r < 16; ++r) {
        const int key0 = kt0 + (r & 3) + 8 * (r >> 2) + 4 * hi;
        float v0 = s0[r] * c1;
        v0 = (key0 <= qrow) ? v0 : -1e30f;
        s0[r] = v0; tmax = fmaxf(tmax, v0);
        float v1 = s1[r] * c1;
        v1 = (key0 + 32 <= qrow) ? v1 : -1e30f;
        s1[r] = v1; tmax = fmaxf(tmax, v1);
      }
      tmax = fmaxf(tmax, __shfl_xor(tmax, 32));

      // online update, unconditional rescale
      const float mn = fmaxf(m, tmax);
      const float alpha = __builtin_amdgcn_exp2f(m - mn);
      m = mn;
      l *= alpha;
      float aw[16];
#pragma unroll
      for (int g = 0; g < 4; ++g)
#pragma unroll
        for (int c = 0; c < 4; ++c)
          aw[g * 4 + c] = __shfl(alpha, g * 8 + hi * 4 + c, 64);
#pragma unroll
      for (int r = 0; r < 16; ++r) {
        const float a2 = aw[(r >> 2) * 4 + (r & 3)];
        oacc[0][r] *= a2; oacc[1][r] *= a2;
        oacc[2][r] *= a2; oacc[3][r] *= a2;
      }

      // P = exp2(s - m), row sum
      float ls = 0.f;
#pragma unroll
      for (int r = 0; r < 16; ++r) {
        const float p0 = __builtin_amdgcn_exp2f(s0[r] - m); s0[r] = p0; ls += p0;
        const float p1 = __builtin_amdgcn_exp2f(s1[r] - m); s1[r] = p1; ls += p1;
      }
      l += ls + __shfl_xor(ls, 32);

      // PV: 4 k-steps of 16 keys; A-words via cvt_pk + lane^32 exchange
#pragma unroll
      for (int t = 0; t < 4; ++t) {
        uint32_t a0, a1, b0, b1;
        if (t == 0) {
          a0 = pk2(s0[0], s0[1]); a1 = pk2(s0[2], s0[3]);
          b0 = pk2(s0[4], s0[5]); b1 = pk2(s0[6], s0[7]);
        } else if (t == 1) {
          a0 = pk2(s0[8], s0[9]); a1 = pk2(s0[10], s0[11]);
          b0 = pk2(s0[12], s0[13]); b1 = pk2(s0[14], s0[15]);
        } else if (t == 2) {
          a0 = pk2(s1[0], s1[1]); a1 = pk2(s1[2], s1[3]);
          b0 = pk2(s1[4], s1[5]); b1 = pk2(s1[6], s1[7]);
        } else {
          a0 = pk2(s1[8], s1[9]); a1 = pk2(s1[10], s1[11]);
          b0 = pk2(s1[12], s1[13]); b1 = pk2(s1[14], s1[15]);
        }
        const uint32_t sa0 = __shfl_xor(a0, 32), sa1 = __shfl_xor(a1, 32);
        const uint32_t sb0 = __shfl_xor(b0, 32), sb1 = __shfl_xor(b1, 32);
        union { uint32_t u[4]; bf16x8 v; } A;
        A.u[0] = hi ? sb0 : a0;
        A.u[1] = hi ? sb1 : a1;
        A.u[2] = hi ? b0 : sa0;
        A.u[3] = hi ? b1 : sa1;
#pragma unroll
        for (int d = 0; d < 4; ++d) {
          const int vrow = d * 32 + l31;
          const int vcb = (32 * t + 16 * hi) ^ ((vrow & 7) << 4);
          bf16x8 vf = *(const bf16x8*)(vb + vrow * 128 + vcb);
          oacc[d] = __builtin_amdgcn_mfma_f32_32x32x16_bf16(A.v, vf, oacc[d], 0, 0, 0);
        }
      }
    }
    __syncthreads();  // all reads of buf done before it is overwritten
  }

  // epilogue: 1/l redistribution + store
  const float linv = 1.0f / l;
  float lw[16];
#pragma unroll
  for (int g = 0; g < 4; ++g)
#pragma unroll
    for (int c = 0; c < 4; ++c)
      lw[g * 4 + c] = __shfl(linv, g * 8 + hi * 4 + c, 64);
  bf16* yb = Y + ((size_t)b * T) * 4096 + h * 128 + l31;
#pragma unroll
  for (int d = 0; d < 4; ++d)
#pragma unroll
    for (int r = 0; r < 16; ++r) {
      const int qp = (r & 3) + 8 * (r >> 2) + 4 * hi;
      const size_t trow = qc * 256 + w * 32 + qp;
      yb[trow * 4096 + d * 32] =
          __float2bfloat16(oacc[d][r] * lw[(r >> 2) * 4 + (r & 3)]);
    }
}

// ---------------- launch ----------------
extern "C" void kernel_launch(void* const* d_in, const int* in_sizes, int n_in,
                              void* d_out, int out_size, void* d_ws, size_t ws_size,
                              hipStream_t stream) {
  const float* x = (const float*)d_in[0];
  const float* fcos = (const float*)d_in[1];
  const float* fsin = (const float*)d_in[2];
  const float* wq = (const float*)d_in[3];
  const float* bq = (const float*)d_in[4];
  const float* wkv = (const float*)d_in[5];
  const float* bkv = (const float*)d_in[6];
  const float* wp = (const float*)d_in[7];
  const float* bp = (const float*)d_in[8];

  char* ws = (char*)d_ws;
  size_t off = 0;
  auto alloc = [&](size_t bytes) {
    char* p = ws + off;
    off += (bytes + 255) & ~(size_t)255;
    return p;
  };
  bf16* xb = (bf16*)alloc(16777216ull * 2);
  bf16* wqb = (bf16*)alloc(16777216ull * 2);
  bf16* wkvb = (bf16*)alloc(8388608ull * 2);
  bf16* wpb = (bf16*)alloc(16777216ull * 2);
  bf16* qb = (bf16*)alloc(16777216ull * 2);
  bf16* kvb = (bf16*)alloc(8388608ull * 2);
  bf16* qr = (bf16*)alloc(16777216ull * 2);
  bf16* kr = (bf16*)alloc(4194304ull * 2);
  bf16* vt = (bf16*)alloc(4194304ull * 2);
  bf16* yb = qb;

  k_cast<<<16384, 256, 0, stream>>>((const float4*)x, (uint2*)xb, 4194304);
  k_cast<<<16384, 256, 0, stream>>>((const float4*)wq, (uint2*)wqb, 4194304);
  k_cast<<<8192, 256, 0, stream>>>((const float4*)wkv, (uint2*)wkvb, 2097152);
  k_cast<<<16384, 256, 0, stream>>>((const float4*)wp, (uint2*)wpb, 4194304);

  k_gemm256<1><<<256, 512, 0, stream>>>(xb, wqb, bq, qb, 4096, 4096, 4096, 16);
  k_gemm256<1><<<128, 512, 0, stream>>>(xb, wkvb, bkv, kvb, 4096, 2048, 4096, 8);

  k_rope_q<<<32768, 256, 0, stream>>>((const uint32_t*)qb, fcos, fsin, (uint32_t*)qr);
  k_rope_k<<<8192, 256, 0, stream>>>((const uint32_t*)kvb, fcos, fsin, (uint32_t*)kr);
  k_vt<<<dim3(32, 16), 256, 0, stream>>>(kvb, vt);

  k_attn<<<512, 512, 0, stream>>>(qr, kr, vt, yb);

  k_gemm256<0><<<256, 512, 0, stream>>>(yb, wpb, bp, d_out, 4096, 4096, 4096, 16);
}

// Round 9
// 525.669 us; speedup vs baseline: 1.7784x; 1.0827x over previous
//
#include <hip/hip_runtime.h>
#include <hip/hip_bf16.h>
#include <stdint.h>

typedef __hip_bfloat16 bf16;
typedef __attribute__((ext_vector_type(8))) __bf16 bf16x8;
typedef __attribute__((ext_vector_type(4))) float f32x4;
typedef __attribute__((ext_vector_type(16))) float f32x16;

__device__ __forceinline__ void gld16(void* lds, const void* g) {
  __builtin_amdgcn_global_load_lds(
      (const __attribute__((address_space(1))) void*)(uintptr_t)(g),
      (__attribute__((address_space(3))) void*)(uint32_t)(uintptr_t)(lds),
      16, 0, 0);
}

__device__ __forceinline__ uint16_t f2bf(float f) {
  union { bf16 h; uint16_t u; } x; x.h = __float2bfloat16(f); return x.u;
}
__device__ __forceinline__ float bf2f(uint16_t v) {
  union { uint32_t u; float f; } x; x.u = ((uint32_t)v) << 16; return x.f;
}
__device__ __forceinline__ uint32_t pk2(float lo, float hi) {
  uint32_t r;
  asm("v_cvt_pk_bf16_f32 %0, %1, %2" : "=v"(r) : "v"(lo), "v"(hi));
  return r;
}

// ---------------- f32 -> bf16 cast (vectorized) ----------------
__global__ __launch_bounds__(256) void k_cast(const float4* __restrict__ in,
                                              uint2* __restrict__ out, int n4) {
  int i = blockIdx.x * 256 + threadIdx.x;
  if (i >= n4) return;
  float4 v = in[i];
  uint32_t a = ((uint32_t)f2bf(v.y) << 16) | f2bf(v.x);
  uint32_t b = ((uint32_t)f2bf(v.w) << 16) | f2bf(v.z);
  out[i] = make_uint2(a, b);
}

// ---------------- 256x256 NT GEMM, de-lockstepped K-loop ----------------
// ONE __syncthreads() per K-tile (slot is stable within a tile, so interval
// barriers are pure overhead: they re-synced all waves into the same region,
// idling the MFMA pipe ~64% -- measured MfmaUtil 36%).  Waves now free-run
// through the 4 MFMA phases; per-wave lgkmcnt(0)+sched_barrier before each
// MFMA group keeps data deps; the single __syncthreads (vmcnt0+lgkm0+barrier,
// proven-safe primitive) establishes: tile t+1 landed, slot-reuse WAR done.
template <int OUT_BF16>
__global__ __launch_bounds__(512, 2) void k_gemm256(
    const bf16* __restrict__ A, const bf16* __restrict__ B,
    const float* __restrict__ bias, void* __restrict__ C,
    int M, int N, int K, int gx) {
  __shared__ __align__(16) char lds[131072];  // [2 slots][A 32KB | B 32KB]
  const int tid = threadIdx.x;
  const int lane = tid & 63;
  const int w = tid >> 6;
  const int wm = w >> 2;
  const int wn = w & 3;
  const int lm = lane & 15;
  const int lg = lane >> 4;

  const int nwg = gridDim.x;
  const int cpx = nwg >> 3;
  const int bid0 = blockIdx.x;
  const int bid = (bid0 & 7) * cpx + (bid0 >> 3);
  const int bx = bid % gx;
  const int by = bid / gx;
  const size_t bm = (size_t)by * 256;
  const size_t bn = (size_t)bx * 256;

  const int srow = tid >> 3;
  const int scb = ((tid & 7) * 16) ^ ((srow & 7) << 4);
  const char* asrc[4];
  const char* bsrc[4];
#pragma unroll
  for (int j = 0; j < 4; ++j) {
    asrc[j] = (const char*)(A + (bm + j * 64 + srow) * K) + scb;
    bsrc[j] = (const char*)(B + (bn + j * 64 + srow) * K) + scb;
  }
  const int ldst = tid * 16;

  const int colb0 = (lg * 16) ^ ((lm & 7) << 4);
  const int colb1 = colb0 ^ 64;

  f32x4 acc[8][4];
#pragma unroll
  for (int i = 0; i < 8; ++i)
#pragma unroll
    for (int j = 0; j < 4; ++j) acc[i][j] = (f32x4){0.f, 0.f, 0.f, 0.f};

  const int NT = K >> 6;

  // prologue: stage tile 0 -> slot 0
  {
    char* la = lds;
    char* lb = lds + 32768;
#pragma unroll
    for (int j = 0; j < 4; ++j) {
      gld16(la + j * 8192 + ldst, asrc[j]);
      gld16(lb + j * 8192 + ldst, bsrc[j]);
    }
  }
  __syncthreads();  // tile 0 landed (vmcnt(0) + barrier)

  for (int t = 0; t < NT; ++t) {
    const int slot = t & 1;
    const char* la = lds + slot * 65536;
    const char* lb = la + 32768;

    // interval-0 reads: all B-frags + A-frags (mi 0,1) -- issue first so
    // their latency starts earliest
    bf16x8 bfrag[4][2];
#pragma unroll
    for (int ni = 0; ni < 4; ++ni) {
      const int br = wn * 64 + ni * 16 + lm;
      bfrag[ni][0] = *(const bf16x8*)(lb + br * 128 + colb0);
      bfrag[ni][1] = *(const bf16x8*)(lb + br * 128 + colb1);
    }
    bf16x8 af[2][2];
#pragma unroll
    for (int q = 0; q < 2; ++q) {
      const int ar = wm * 128 + q * 16 + lm;
      af[q][0] = *(const bf16x8*)(la + ar * 128 + colb0);
      af[q][1] = *(const bf16x8*)(la + ar * 128 + colb1);
    }

    if (t + 1 < NT) {
      // stage tile t+1 into the other slot (VMEM issue, overlaps ds/MFMA)
      char* na = lds + (slot ^ 1) * 65536;
      char* nb = na + 32768;
      const size_t ko = (size_t)(t + 1) * 128;
#pragma unroll
      for (int j = 0; j < 4; ++j) {
        gld16(na + j * 8192 + ldst, asrc[j] + ko);
        gld16(nb + j * 8192 + ldst, bsrc[j] + ko);
      }
    }

#pragma unroll
    for (int p = 0; p < 4; ++p) {
      asm volatile("s_waitcnt lgkmcnt(0)" ::: "memory");
      __builtin_amdgcn_sched_barrier(0);
      __builtin_amdgcn_s_setprio(1);
      bf16x8 a00 = af[0][0], a01 = af[0][1];
      bf16x8 a10 = af[1][0], a11 = af[1][1];
#pragma unroll
      for (int ni = 0; ni < 4; ++ni) {
        acc[2 * p][ni] = __builtin_amdgcn_mfma_f32_16x16x32_bf16(
            a00, bfrag[ni][0], acc[2 * p][ni], 0, 0, 0);
        acc[2 * p][ni] = __builtin_amdgcn_mfma_f32_16x16x32_bf16(
            a01, bfrag[ni][1], acc[2 * p][ni], 0, 0, 0);
        acc[2 * p + 1][ni] = __builtin_amdgcn_mfma_f32_16x16x32_bf16(
            a10, bfrag[ni][0], acc[2 * p + 1][ni], 0, 0, 0);
        acc[2 * p + 1][ni] = __builtin_amdgcn_mfma_f32_16x16x32_bf16(
            a11, bfrag[ni][1], acc[2 * p + 1][ni], 0, 0, 0);
      }
      __builtin_amdgcn_s_setprio(0);
      if (p < 3) {
        // A-frags for interval p+1 (same stable slot; no barrier needed)
#pragma unroll
        for (int q = 0; q < 2; ++q) {
          const int ar = wm * 128 + (2 * (p + 1) + q) * 16 + lm;
          af[q][0] = *(const bf16x8*)(la + ar * 128 + colb0);
          af[q][1] = *(const bf16x8*)(la + ar * 128 + colb1);
        }
      }
    }
    // single sync: drains vmcnt (t+1 staged ~1 tile ago -> nearly free) and
    // joins all waves: t+1 visible, all reads of slot^1's old content done.
    __syncthreads();
  }

#pragma unroll
  for (int ni = 0; ni < 4; ++ni) {
    const size_t col = bn + wn * 64 + ni * 16 + lm;
    const float bv = bias[col];
#pragma unroll
    for (int mi = 0; mi < 8; ++mi) {
#pragma unroll
      for (int r = 0; r < 4; ++r) {
        const size_t row = bm + wm * 128 + mi * 16 + lg * 4 + r;
        const float v = acc[mi][ni][r] + bv;
        if (OUT_BF16)
          ((bf16*)C)[row * N + col] = __float2bfloat16(v);
        else
          ((float*)C)[row * N + col] = v;
      }
    }
  }
}

// ---------------- RoPE on Q: [b][t][h*128+d] -> [b][h][t][d] ----------------
__global__ __launch_bounds__(256) void k_rope_q(
    const uint32_t* __restrict__ qin, const float* __restrict__ fc,
    const float* __restrict__ fs, uint32_t* __restrict__ qout) {
  const int tid = blockIdx.x * 256 + threadIdx.x;
  const int i = tid & 63;
  const int h = (tid >> 6) & 31;
  const int t = (tid >> 11) & 2047;
  const int b = tid >> 22;
  const uint32_t u = qin[tid];
  const float t0 = bf2f((uint16_t)(u & 0xffff));
  const float t1 = bf2f((uint16_t)(u >> 16));
  const float c = fc[t * 64 + i];
  const float s = fs[t * 64 + i];
  const float r0 = t0 * c - t1 * s;
  const float r1 = t0 * s + t1 * c;
  const uint32_t o = ((uint32_t)f2bf(r1) << 16) | f2bf(r0);
  qout[(((size_t)(b * 32 + h)) * 2048 + t) * 64 + i] = o;
}

// ---------------- RoPE on K part of KV ----------------
__global__ __launch_bounds__(256) void k_rope_k(
    const uint32_t* __restrict__ kvin, const float* __restrict__ fc,
    const float* __restrict__ fs, uint32_t* __restrict__ kout) {
  const int tid = blockIdx.x * 256 + threadIdx.x;
  const int i = tid & 63;
  const int kvh = (tid >> 6) & 7;
  const int t = (tid >> 9) & 2047;
  const int b = tid >> 20;
  const uint32_t u = kvin[((size_t)(b * 2048 + t)) * 1024 + kvh * 64 + i];
  const float t0 = bf2f((uint16_t)(u & 0xffff));
  const float t1 = bf2f((uint16_t)(u >> 16));
  const float c = fc[t * 64 + i];
  const float s = fs[t * 64 + i];
  const float r0 = t0 * c - t1 * s;
  const float r1 = t0 * s + t1 * c;
  const uint32_t o = ((uint32_t)f2bf(r1) << 16) | f2bf(r0);
  kout[(((size_t)(b * 8 + kvh)) * 2048 + t) * 64 + i] = o;
}

// ---------------- V transpose -> [b][kvh][d][t] ----------------
__global__ __launch_bounds__(256) void k_vt(const bf16* __restrict__ kv,
                                            bf16* __restrict__ vt) {
  __shared__ __align__(16) bf16 tile[64][130];
  const int bh = blockIdx.y;
  const int b = bh >> 3, kvh = bh & 7;
  const int t0 = blockIdx.x * 64;
  const int tid = threadIdx.x;
  const int d0 = (tid & 15) * 8;
  const int tr = tid >> 4;
#pragma unroll
  for (int j = 0; j < 4; ++j) {
    const int trow = tr + j * 16;
    const bf16* src =
        kv + ((size_t)(b * 2048) + t0 + trow) * 2048 + 1024 + kvh * 128 + d0;
    uint4 v = *(const uint4*)src;
    uint32_t* dst = (uint32_t*)&tile[trow][d0];
    dst[0] = v.x; dst[1] = v.y; dst[2] = v.z; dst[3] = v.w;
  }
  __syncthreads();
  const int d = tid >> 1;
  const int th = (tid & 1) * 32;
  uint4* out = (uint4*)(vt + (((size_t)bh) * 128 + d) * 2048 + t0 + th);
  union { bf16 h; uint16_t u; } cv;
#pragma unroll
  for (int j = 0; j < 4; ++j) {
    uint32_t wds[4];
#pragma unroll
    for (int p = 0; p < 4; ++p) {
      cv.h = tile[th + j * 8 + p * 2][d];
      uint32_t lo = cv.u;
      cv.h = tile[th + j * 8 + p * 2 + 1][d];
      wds[p] = lo | ((uint32_t)cv.u << 16);
    }
    uint4 val; val.x = wds[0]; val.y = wds[1]; val.z = wds[2]; val.w = wds[3];
    out[j] = val;
  }
}

// ---------------- causal GQA flash attention, 8-warp 32x32 swapped-QK^T ----
// SAFE-SYNC (round-7 verified form, unchanged).
__global__ __launch_bounds__(512) void k_attn(
    const bf16* __restrict__ Q, const bf16* __restrict__ Kr,
    const bf16* __restrict__ Vt, bf16* __restrict__ Y) {
  constexpr int T = 2048;
  __shared__ __align__(16) char lds[65536];  // [2][K 16KB | V 16KB]
  const int tid = threadIdx.x;
  const int lane = tid & 63;
  const int w = tid >> 6;
  const int l31 = lane & 31;
  const int hi = lane >> 5;

  const int n = blockIdx.x;
  const int qc = 7 - (n >> 6);  // heavy-first
  const int bh = n & 63;
  const int b = bh >> 5, h = bh & 31, kvh = h >> 2;

  const int qrow = qc * 256 + w * 32 + l31;
  const int qmaxw = qc * 256 + w * 32 + 31;
  const int NT = qc * 4 + 4;

  const bf16* qptr = Q + (((size_t)(b * 32 + h)) * T + qrow) * 128 + hi * 8;
  bf16x8 qf[8];
#pragma unroll
  for (int kt = 0; kt < 8; ++kt) qf[kt] = *(const bf16x8*)(qptr + kt * 16);

  const char* kg = (const char*)(Kr + ((size_t)(b * 8 + kvh)) * T * 128);
  const char* vg = (const char*)(Vt + ((size_t)(b * 8 + kvh)) * 128 * T);
  const char* ksrc[2];
  const char* vsrc[2];
  int kdst[2], vdst[2];
#pragma unroll
  for (int j = 0; j < 2; ++j) {
    const int o = j * 8192 + tid * 16;
    const int krow = o >> 8, kin = o & 255;
    ksrc[j] = kg + (size_t)krow * 256 + (kin ^ ((krow & 15) << 4));
    kdst[j] = o;
    const int vrow = o >> 7, vin = o & 127;
    vsrc[j] = vg + (size_t)vrow * (T * 2) + (vin ^ ((vrow & 7) << 4));
    vdst[j] = 16384 + o;
  }

  f32x16 oacc[4];
#pragma unroll
  for (int d = 0; d < 4; ++d)
#pragma unroll
    for (int r = 0; r < 16; ++r) oacc[d][r] = 0.f;
  float m = -1e30f, l = 0.f;
  const float c1 = 0.08838834764831845f * 1.44269504089f;  // scale*log2e

  // prologue: stage tile 0 -> buf 0
#pragma unroll
  for (int j = 0; j < 2; ++j) {
    gld16(lds + kdst[j], ksrc[j]);
    gld16(lds + vdst[j], vsrc[j]);
  }

  for (int it = 0; it < NT; ++it) {
    const int buf = it & 1;
    __syncthreads();  // drains all vmcnt (tile-it staging) + block barrier

    if (it + 1 < NT) {  // stage next tile into the other buffer (overlaps)
      const int nb = buf ^ 1;
      const size_t ko = (size_t)(it + 1) * 16384;
      const size_t vo = (size_t)(it + 1) * 128;
#pragma unroll
      for (int j = 0; j < 2; ++j) {
        gld16(lds + nb * 32768 + kdst[j], ksrc[j] + ko);
        gld16(lds + nb * 32768 + vdst[j], vsrc[j] + vo);
      }
    }

    const int kt0 = it * 64;
    if (kt0 <= qmaxw) {  // warp-uniform: skip fully-masked tiles
      const char* kb = lds + buf * 32768;
      const char* vb = kb + 16384;

      // S^T = K Q^T  (two 32-key subtiles)
      f32x16 s0, s1;
#pragma unroll
      for (int r = 0; r < 16; ++r) { s0[r] = 0.f; s1[r] = 0.f; }
      const int kswz = (l31 & 15) << 4;
#pragma unroll
      for (int kt = 0; kt < 8; ++kt) {
        const int cb = (kt * 32 + hi * 16) ^ kswz;
        bf16x8 kf0 = *(const bf16x8*)(kb + l31 * 256 + cb);
        bf16x8 kf1 = *(const bf16x8*)(kb + (32 + l31) * 256 + cb);
        s0 = __builtin_amdgcn_mfma_f32_32x32x16_bf16(kf0, qf[kt], s0, 0, 0, 0);
        s1 = __builtin_amdgcn_mfma_f32_32x32x16_bf16(kf1, qf[kt], s1, 0, 0, 0);
      }

      // mask + scale (log2 units) + row max
      float tmax = -1e30f;
#pragma unroll
      for (int r = 0; r < 16; ++r) {
        const int key0 = kt0 + (r & 3) + 8 * (r >> 2) + 4 * hi;
        float v0 = s0[r] * c1;
        v0 = (key0 <= qrow) ? v0 : -1e30f;
        s0[r] = v0; tmax = fmaxf(tmax, v0);
        float v1 = s1[r] * c1;
        v1 = (key0 + 32 <= qrow) ? v1 : -1e30f;
        s1[r] = v1; tmax = fmaxf(tmax, v1);
      }
      tmax = fmaxf(tmax, __shfl_xor(tmax, 32));

      // online update, unconditional rescale
      const float mn = fmaxf(m, tmax);
      const float alpha = __builtin_amdgcn_exp2f(m - mn);
      m = mn;
      l *= alpha;
      float aw[16];
#pragma unroll
      for (int g = 0; g < 4; ++g)
#pragma unroll
        for (int c = 0; c < 4; ++c)
          aw[g * 4 + c] = __shfl(alpha, g * 8 + hi * 4 + c, 64);
#pragma unroll
      for (int r = 0; r < 16; ++r) {
        const float a2 = aw[(r >> 2) * 4 + (r & 3)];
        oacc[0][r] *= a2; oacc[1][r] *= a2;
        oacc[2][r] *= a2; oacc[3][r] *= a2;
      }

      // P = exp2(s - m), row sum
      float ls = 0.f;
#pragma unroll
      for (int r = 0; r < 16; ++r) {
        const float p0 = __builtin_amdgcn_exp2f(s0[r] - m); s0[r] = p0; ls += p0;
        const float p1 = __builtin_amdgcn_exp2f(s1[r] - m); s1[r] = p1; ls += p1;
      }
      l += ls + __shfl_xor(ls, 32);

      // PV: 4 k-steps of 16 keys; A-words via cvt_pk + lane^32 exchange
#pragma unroll
      for (int t = 0; t < 4; ++t) {
        uint32_t a0, a1, b0, b1;
        if (t == 0) {
          a0 = pk2(s0[0], s0[1]); a1 = pk2(s0[2], s0[3]);
          b0 = pk2(s0[4], s0[5]); b1 = pk2(s0[6], s0[7]);
        } else if (t == 1) {
          a0 = pk2(s0[8], s0[9]); a1 = pk2(s0[10], s0[11]);
          b0 = pk2(s0[12], s0[13]); b1 = pk2(s0[14], s0[15]);
        } else if (t == 2) {
          a0 = pk2(s1[0], s1[1]); a1 = pk2(s1[2], s1[3]);
          b0 = pk2(s1[4], s1[5]); b1 = pk2(s1[6], s1[7]);
        } else {
          a0 = pk2(s1[8], s1[9]); a1 = pk2(s1[10], s1[11]);
          b0 = pk2(s1[12], s1[13]); b1 = pk2(s1[14], s1[15]);
        }
        const uint32_t sa0 = __shfl_xor(a0, 32), sa1 = __shfl_xor(a1, 32);
        const uint32_t sb0 = __shfl_xor(b0, 32), sb1 = __shfl_xor(b1, 32);
        union { uint32_t u[4]; bf16x8 v; } A;
        A.u[0] = hi ? sb0 : a0;
        A.u[1] = hi ? sb1 : a1;
        A.u[2] = hi ? b0 : sa0;
        A.u[3] = hi ? b1 : sa1;
#pragma unroll
        for (int d = 0; d < 4; ++d) {
          const int vrow = d * 32 + l31;
          const int vcb = (32 * t + 16 * hi) ^ ((vrow & 7) << 4);
          bf16x8 vf = *(const bf16x8*)(vb + vrow * 128 + vcb);
          oacc[d] = __builtin_amdgcn_mfma_f32_32x32x16_bf16(A.v, vf, oacc[d], 0, 0, 0);
        }
      }
    }
    __syncthreads();  // all reads of buf done before it is overwritten
  }

  // epilogue: 1/l redistribution + store
  const float linv = 1.0f / l;
  float lw[16];
#pragma unroll
  for (int g = 0; g < 4; ++g)
#pragma unroll
    for (int c = 0; c < 4; ++c)
      lw[g * 4 + c] = __shfl(linv, g * 8 + hi * 4 + c, 64);
  bf16* yb = Y + ((size_t)b * T) * 4096 + h * 128 + l31;
#pragma unroll
  for (int d = 0; d < 4; ++d)
#pragma unroll
    for (int r = 0; r < 16; ++r) {
      const int qp = (r & 3) + 8 * (r >> 2) + 4 * hi;
      const size_t trow = qc * 256 + w * 32 + qp;
      yb[trow * 4096 + d * 32] =
          __float2bfloat16(oacc[d][r] * lw[(r >> 2) * 4 + (r & 3)]);
    }
}

// ---------------- launch ----------------
extern "C" void kernel_launch(void* const* d_in, const int* in_sizes, int n_in,
                              void* d_out, int out_size, void* d_ws, size_t ws_size,
                              hipStream_t stream) {
  const float* x = (const float*)d_in[0];
  const float* fcos = (const float*)d_in[1];
  const float* fsin = (const float*)d_in[2];
  const float* wq = (const float*)d_in[3];
  const float* bq = (const float*)d_in[4];
  const float* wkv = (const float*)d_in[5];
  const float* bkv = (const float*)d_in[6];
  const float* wp = (const float*)d_in[7];
  const float* bp = (const float*)d_in[8];

  char* ws = (char*)d_ws;
  size_t off = 0;
  auto alloc = [&](size_t bytes) {
    char* p = ws + off;
    off += (bytes + 255) & ~(size_t)255;
    return p;
  };
  bf16* xb = (bf16*)alloc(16777216ull * 2);
  bf16* wqb = (bf16*)alloc(16777216ull * 2);
  bf16* wkvb = (bf16*)alloc(8388608ull * 2);
  bf16* wpb = (bf16*)alloc(16777216ull * 2);
  bf16* qb = (bf16*)alloc(16777216ull * 2);
  bf16* kvb = (bf16*)alloc(8388608ull * 2);
  bf16* qr = (bf16*)alloc(16777216ull * 2);
  bf16* kr = (bf16*)alloc(4194304ull * 2);
  bf16* vt = (bf16*)alloc(4194304ull * 2);
  bf16* yb = qb;

  k_cast<<<16384, 256, 0, stream>>>((const float4*)x, (uint2*)xb, 4194304);
  k_cast<<<16384, 256, 0, stream>>>((const float4*)wq, (uint2*)wqb, 4194304);
  k_cast<<<8192, 256, 0, stream>>>((const float4*)wkv, (uint2*)wkvb, 2097152);
  k_cast<<<16384, 256, 0, stream>>>((const float4*)wp, (uint2*)wpb, 4194304);

  k_gemm256<1><<<256, 512, 0, stream>>>(xb, wqb, bq, qb, 4096, 4096, 4096, 16);
  k_gemm256<1><<<128, 512, 0, stream>>>(xb, wkvb, bkv, kvb, 4096, 2048, 4096, 8);

  k_rope_q<<<32768, 256, 0, stream>>>((const uint32_t*)qb, fcos, fsin, (uint32_t*)qr);
  k_rope_k<<<8192, 256, 0, stream>>>((const uint32_t*)kvb, fcos, fsin, (uint32_t*)kr);
  k_vt<<<dim3(32, 16), 256, 0, stream>>>(kvb, vt);

  k_attn<<<512, 512, 0, stream>>>(qr, kr, vt, yb);

  k_gemm256<0><<<256, 512, 0, stream>>>(yb, wpb, bp, d_out, 4096, 4096, 4096, 16);
}

// Round 10
// 516.997 us; speedup vs baseline: 1.8082x; 1.0168x over previous
//
#include <hip/hip_runtime.h>
#include <hip/hip_bf16.h>
#include <stdint.h>

typedef __hip_bfloat16 bf16;
typedef __attribute__((ext_vector_type(8))) __bf16 bf16x8;
typedef __attribute__((ext_vector_type(4))) float f32x4;
typedef __attribute__((ext_vector_type(16))) float f32x16;

__device__ __forceinline__ void gld16(void* lds, const void* g) {
  __builtin_amdgcn_global_load_lds(
      (const __attribute__((address_space(1))) void*)(uintptr_t)(g),
      (__attribute__((address_space(3))) void*)(uint32_t)(uintptr_t)(lds),
      16, 0, 0);
}

__device__ __forceinline__ uint16_t f2bf(float f) {
  union { bf16 h; uint16_t u; } x; x.h = __float2bfloat16(f); return x.u;
}
__device__ __forceinline__ float bf2f(uint16_t v) {
  union { uint32_t u; float f; } x; x.u = ((uint32_t)v) << 16; return x.f;
}
__device__ __forceinline__ uint32_t pk2(float lo, float hi) {
  uint32_t r;
  asm("v_cvt_pk_bf16_f32 %0, %1, %2" : "=v"(r) : "v"(lo), "v"(hi));
  return r;
}

// ---------------- f32 -> bf16 cast (vectorized) ----------------
__global__ __launch_bounds__(256) void k_cast(const float4* __restrict__ in,
                                              uint2* __restrict__ out, int n4) {
  int i = blockIdx.x * 256 + threadIdx.x;
  if (i >= n4) return;
  float4 v = in[i];
  uint32_t a = ((uint32_t)f2bf(v.y) << 16) | f2bf(v.x);
  uint32_t b = ((uint32_t)f2bf(v.w) << 16) | f2bf(v.z);
  out[i] = make_uint2(a, b);
}

// ---------------- bias concat: [bq(4096) | bkv(2048)] ----------------
__global__ __launch_bounds__(256) void k_bcat(const float* __restrict__ bq,
                                              const float* __restrict__ bkv,
                                              float* __restrict__ o) {
  const int i = blockIdx.x * 256 + threadIdx.x;  // 6144
  o[i] = (i < 4096) ? bq[i] : bkv[i - 4096];
}

// ---------------- 256x256 NT GEMM, counted-lgkm pipelined K-loop ----------
// One __syncthreads per K-tile (round-9 verified de-lockstep).  NEW: A-frag
// reads for phase p+1 are issued into a ping-pong register buffer BEFORE the
// wait, then s_waitcnt lgkmcnt(4) (DS ops retire in-order -> exactly the 4
// just-issued reads may remain outstanding) so read latency hides under the
// MFMA burst instead of serializing with it (round-9: LDS+MFMA cycles summed).
template <int OUT_BF16>
__global__ __launch_bounds__(512, 2) void k_gemm256(
    const bf16* __restrict__ A, const bf16* __restrict__ B,
    const float* __restrict__ bias, void* __restrict__ C,
    int M, int N, int K, int gx) {
  __shared__ __align__(16) char lds[131072];  // [2 slots][A 32KB | B 32KB]
  const int tid = threadIdx.x;
  const int lane = tid & 63;
  const int w = tid >> 6;
  const int wm = w >> 2;
  const int wn = w & 3;
  const int lm = lane & 15;
  const int lg = lane >> 4;

  const int nwg = gridDim.x;
  const int cpx = nwg >> 3;
  const int bid0 = blockIdx.x;
  const int bid = (bid0 & 7) * cpx + (bid0 >> 3);
  const int bx = bid % gx;
  const int by = bid / gx;
  const size_t bm = (size_t)by * 256;
  const size_t bn = (size_t)bx * 256;

  const int srow = tid >> 3;
  const int scb = ((tid & 7) * 16) ^ ((srow & 7) << 4);
  const char* asrc[4];
  const char* bsrc[4];
#pragma unroll
  for (int j = 0; j < 4; ++j) {
    asrc[j] = (const char*)(A + (bm + j * 64 + srow) * K) + scb;
    bsrc[j] = (const char*)(B + (bn + j * 64 + srow) * K) + scb;
  }
  const int ldst = tid * 16;

  const int colb0 = (lg * 16) ^ ((lm & 7) << 4);
  const int colb1 = colb0 ^ 64;

  f32x4 acc[8][4];
#pragma unroll
  for (int i = 0; i < 8; ++i)
#pragma unroll
    for (int j = 0; j < 4; ++j) acc[i][j] = (f32x4){0.f, 0.f, 0.f, 0.f};

  const int NT = K >> 6;

  // prologue: stage tile 0 -> slot 0
  {
    char* la = lds;
    char* lb = lds + 32768;
#pragma unroll
    for (int j = 0; j < 4; ++j) {
      gld16(la + j * 8192 + ldst, asrc[j]);
      gld16(lb + j * 8192 + ldst, bsrc[j]);
    }
  }
  __syncthreads();  // tile 0 landed

  for (int t = 0; t < NT; ++t) {
    const int slot = t & 1;
    const char* la = lds + slot * 65536;
    const char* lb = la + 32768;

    // tile top: all B-frags + A-frags for phase 0 (earliest latency start)
    bf16x8 bfrag[4][2];
#pragma unroll
    for (int ni = 0; ni < 4; ++ni) {
      const int br = wn * 64 + ni * 16 + lm;
      bfrag[ni][0] = *(const bf16x8*)(lb + br * 128 + colb0);
      bfrag[ni][1] = *(const bf16x8*)(lb + br * 128 + colb1);
    }
    bf16x8 afA[2][2], afB[2][2];
#pragma unroll
    for (int q = 0; q < 2; ++q) {
      const int ar = wm * 128 + q * 16 + lm;
      afA[q][0] = *(const bf16x8*)(la + ar * 128 + colb0);
      afA[q][1] = *(const bf16x8*)(la + ar * 128 + colb1);
    }

    if (t + 1 < NT) {
      char* na = lds + (slot ^ 1) * 65536;
      char* nb = na + 32768;
      const size_t ko = (size_t)(t + 1) * 128;
#pragma unroll
      for (int j = 0; j < 4; ++j) {
        gld16(na + j * 8192 + ldst, asrc[j] + ko);
        gld16(nb + j * 8192 + ldst, bsrc[j] + ko);
      }
    }

#pragma unroll
    for (int p = 0; p < 4; ++p) {
      auto& cur = (p & 1) ? afB : afA;
      auto& nxt = (p & 1) ? afA : afB;
      if (p < 3) {
        // issue phase-(p+1) A-frag reads, then wait for all EXCEPT them
#pragma unroll
        for (int q = 0; q < 2; ++q) {
          const int ar = wm * 128 + (2 * (p + 1) + q) * 16 + lm;
          nxt[q][0] = *(const bf16x8*)(la + ar * 128 + colb0);
          nxt[q][1] = *(const bf16x8*)(la + ar * 128 + colb1);
        }
        asm volatile("s_waitcnt lgkmcnt(4)" ::: "memory");
      } else {
        asm volatile("s_waitcnt lgkmcnt(0)" ::: "memory");
      }
      __builtin_amdgcn_sched_barrier(0);
      __builtin_amdgcn_s_setprio(1);
      bf16x8 a00 = cur[0][0], a01 = cur[0][1];
      bf16x8 a10 = cur[1][0], a11 = cur[1][1];
#pragma unroll
      for (int ni = 0; ni < 4; ++ni) {
        acc[2 * p][ni] = __builtin_amdgcn_mfma_f32_16x16x32_bf16(
            a00, bfrag[ni][0], acc[2 * p][ni], 0, 0, 0);
        acc[2 * p][ni] = __builtin_amdgcn_mfma_f32_16x16x32_bf16(
            a01, bfrag[ni][1], acc[2 * p][ni], 0, 0, 0);
        acc[2 * p + 1][ni] = __builtin_amdgcn_mfma_f32_16x16x32_bf16(
            a10, bfrag[ni][0], acc[2 * p + 1][ni], 0, 0, 0);
        acc[2 * p + 1][ni] = __builtin_amdgcn_mfma_f32_16x16x32_bf16(
            a11, bfrag[ni][1], acc[2 * p + 1][ni], 0, 0, 0);
      }
      __builtin_amdgcn_s_setprio(0);
    }
    __syncthreads();  // t+1 landed + slot-reuse WAR done
  }

#pragma unroll
  for (int ni = 0; ni < 4; ++ni) {
    const size_t col = bn + wn * 64 + ni * 16 + lm;
    const float bv = bias[col];
#pragma unroll
    for (int mi = 0; mi < 8; ++mi) {
#pragma unroll
      for (int r = 0; r < 4; ++r) {
        const size_t row = bm + wm * 128 + mi * 16 + lg * 4 + r;
        const float v = acc[mi][ni][r] + bv;
        if (OUT_BF16)
          ((bf16*)C)[row * N + col] = __float2bfloat16(v);
        else
          ((float*)C)[row * N + col] = v;
      }
    }
  }
}

// ---------------- RoPE on Q from fused qkv [b][t][6144]: -> [b][h][t][d] ----
__global__ __launch_bounds__(256) void k_rope_q(
    const uint32_t* __restrict__ qkv, const float* __restrict__ fc,
    const float* __restrict__ fs, uint32_t* __restrict__ qout) {
  const int tid = blockIdx.x * 256 + threadIdx.x;  // 2*2048*32*64
  const int i = tid & 63;
  const int h = (tid >> 6) & 31;
  const int t = (tid >> 11) & 2047;
  const int b = tid >> 22;
  const uint32_t u = qkv[((size_t)(b * 2048 + t)) * 3072 + h * 64 + i];
  const float t0 = bf2f((uint16_t)(u & 0xffff));
  const float t1 = bf2f((uint16_t)(u >> 16));
  const float c = fc[t * 64 + i];
  const float s = fs[t * 64 + i];
  const float r0 = t0 * c - t1 * s;
  const float r1 = t0 * s + t1 * c;
  const uint32_t o = ((uint32_t)f2bf(r1) << 16) | f2bf(r0);
  qout[(((size_t)(b * 32 + h)) * 2048 + t) * 64 + i] = o;
}

// ---------------- RoPE on K from fused qkv (cols 4096..5119) ----------------
__global__ __launch_bounds__(256) void k_rope_k(
    const uint32_t* __restrict__ qkv, const float* __restrict__ fc,
    const float* __restrict__ fs, uint32_t* __restrict__ kout) {
  const int tid = blockIdx.x * 256 + threadIdx.x;  // 2*2048*8*64
  const int i = tid & 63;
  const int kvh = (tid >> 6) & 7;
  const int t = (tid >> 9) & 2047;
  const int b = tid >> 20;
  const uint32_t u =
      qkv[((size_t)(b * 2048 + t)) * 3072 + 2048 + kvh * 64 + i];
  const float t0 = bf2f((uint16_t)(u & 0xffff));
  const float t1 = bf2f((uint16_t)(u >> 16));
  const float c = fc[t * 64 + i];
  const float s = fs[t * 64 + i];
  const float r0 = t0 * c - t1 * s;
  const float r1 = t0 * s + t1 * c;
  const uint32_t o = ((uint32_t)f2bf(r1) << 16) | f2bf(r0);
  kout[(((size_t)(b * 8 + kvh)) * 2048 + t) * 64 + i] = o;
}

// ---------------- V transpose from fused qkv (cols 5120..6143) -> [b][kvh][d][t]
__global__ __launch_bounds__(256) void k_vt(const bf16* __restrict__ qkv,
                                            bf16* __restrict__ vt) {
  __shared__ __align__(16) bf16 tile[64][130];
  const int bh = blockIdx.y;
  const int b = bh >> 3, kvh = bh & 7;
  const int t0 = blockIdx.x * 64;
  const int tid = threadIdx.x;
  const int d0 = (tid & 15) * 8;
  const int tr = tid >> 4;
#pragma unroll
  for (int j = 0; j < 4; ++j) {
    const int trow = tr + j * 16;
    const bf16* src =
        qkv + ((size_t)(b * 2048) + t0 + trow) * 6144 + 5120 + kvh * 128 + d0;
    uint4 v = *(const uint4*)src;
    uint32_t* dst = (uint32_t*)&tile[trow][d0];
    dst[0] = v.x; dst[1] = v.y; dst[2] = v.z; dst[3] = v.w;
  }
  __syncthreads();
  const int d = tid >> 1;
  const int th = (tid & 1) * 32;
  uint4* out = (uint4*)(vt + (((size_t)bh) * 128 + d) * 2048 + t0 + th);
  union { bf16 h; uint16_t u; } cv;
#pragma unroll
  for (int j = 0; j < 4; ++j) {
    uint32_t wds[4];
#pragma unroll
    for (int p = 0; p < 4; ++p) {
      cv.h = tile[th + j * 8 + p * 2][d];
      uint32_t lo = cv.u;
      cv.h = tile[th + j * 8 + p * 2 + 1][d];
      wds[p] = lo | ((uint32_t)cv.u << 16);
    }
    uint4 val; val.x = wds[0]; val.y = wds[1]; val.z = wds[2]; val.w = wds[3];
    out[j] = val;
  }
}

// ---------------- causal GQA flash attention, 8-warp 32x32 swapped-QK^T ----
// SAFE-SYNC (round-7 verified form, unchanged).
__global__ __launch_bounds__(512) void k_attn(
    const bf16* __restrict__ Q, const bf16* __restrict__ Kr,
    const bf16* __restrict__ Vt, bf16* __restrict__ Y) {
  constexpr int T = 2048;
  __shared__ __align__(16) char lds[65536];  // [2][K 16KB | V 16KB]
  const int tid = threadIdx.x;
  const int lane = tid & 63;
  const int w = tid >> 6;
  const int l31 = lane & 31;
  const int hi = lane >> 5;

  const int n = blockIdx.x;
  const int qc = 7 - (n >> 6);  // heavy-first
  const int bh = n & 63;
  const int b = bh >> 5, h = bh & 31, kvh = h >> 2;

  const int qrow = qc * 256 + w * 32 + l31;
  const int qmaxw = qc * 256 + w * 32 + 31;
  const int NT = qc * 4 + 4;

  const bf16* qptr = Q + (((size_t)(b * 32 + h)) * T + qrow) * 128 + hi * 8;
  bf16x8 qf[8];
#pragma unroll
  for (int kt = 0; kt < 8; ++kt) qf[kt] = *(const bf16x8*)(qptr + kt * 16);

  const char* kg = (const char*)(Kr + ((size_t)(b * 8 + kvh)) * T * 128);
  const char* vg = (const char*)(Vt + ((size_t)(b * 8 + kvh)) * 128 * T);
  const char* ksrc[2];
  const char* vsrc[2];
  int kdst[2], vdst[2];
#pragma unroll
  for (int j = 0; j < 2; ++j) {
    const int o = j * 8192 + tid * 16;
    const int krow = o >> 8, kin = o & 255;
    ksrc[j] = kg + (size_t)krow * 256 + (kin ^ ((krow & 15) << 4));
    kdst[j] = o;
    const int vrow = o >> 7, vin = o & 127;
    vsrc[j] = vg + (size_t)vrow * (T * 2) + (vin ^ ((vrow & 7) << 4));
    vdst[j] = 16384 + o;
  }

  f32x16 oacc[4];
#pragma unroll
  for (int d = 0; d < 4; ++d)
#pragma unroll
    for (int r = 0; r < 16; ++r) oacc[d][r] = 0.f;
  float m = -1e30f, l = 0.f;
  const float c1 = 0.08838834764831845f * 1.44269504089f;  // scale*log2e

  // prologue: stage tile 0 -> buf 0
#pragma unroll
  for (int j = 0; j < 2; ++j) {
    gld16(lds + kdst[j], ksrc[j]);
    gld16(lds + vdst[j], vsrc[j]);
  }

  for (int it = 0; it < NT; ++it) {
    const int buf = it & 1;
    __syncthreads();  // drains all vmcnt (tile-it staging) + block barrier

    if (it + 1 < NT) {  // stage next tile into the other buffer (overlaps)
      const int nb = buf ^ 1;
      const size_t ko = (size_t)(it + 1) * 16384;
      const size_t vo = (size_t)(it + 1) * 128;
#pragma unroll
      for (int j = 0; j < 2; ++j) {
        gld16(lds + nb * 32768 + kdst[j], ksrc[j] + ko);
        gld16(lds + nb * 32768 + vdst[j], vsrc[j] + vo);
      }
    }

    const int kt0 = it * 64;
    if (kt0 <= qmaxw) {  // warp-uniform: skip fully-masked tiles
      const char* kb = lds + buf * 32768;
      const char* vb = kb + 16384;

      // S^T = K Q^T  (two 32-key subtiles)
      f32x16 s0, s1;
#pragma unroll
      for (int r = 0; r < 16; ++r) { s0[r] = 0.f; s1[r] = 0.f; }
      const int kswz = (l31 & 15) << 4;
#pragma unroll
      for (int kt = 0; kt < 8; ++kt) {
        const int cb = (kt * 32 + hi * 16) ^ kswz;
        bf16x8 kf0 = *(const bf16x8*)(kb + l31 * 256 + cb);
        bf16x8 kf1 = *(const bf16x8*)(kb + (32 + l31) * 256 + cb);
        s0 = __builtin_amdgcn_mfma_f32_32x32x16_bf16(kf0, qf[kt], s0, 0, 0, 0);
        s1 = __builtin_amdgcn_mfma_f32_32x32x16_bf16(kf1, qf[kt], s1, 0, 0, 0);
      }

      // mask + scale (log2 units) + row max
      float tmax = -1e30f;
#pragma unroll
      for (int r = 0; r < 16; ++r) {
        const int key0 = kt0 + (r & 3) + 8 * (r >> 2) + 4 * hi;
        float v0 = s0[r] * c1;
        v0 = (key0 <= qrow) ? v0 : -1e30f;
        s0[r] = v0; tmax = fmaxf(tmax, v0);
        float v1 = s1[r] * c1;
        v1 = (key0 + 32 <= qrow) ? v1 : -1e30f;
        s1[r] = v1; tmax = fmaxf(tmax, v1);
      }
      tmax = fmaxf(tmax, __shfl_xor(tmax, 32));

      // online update, unconditional rescale
      const float mn = fmaxf(m, tmax);
      const float alpha = __builtin_amdgcn_exp2f(m - mn);
      m = mn;
      l *= alpha;
      float aw[16];
#pragma unroll
      for (int g = 0; g < 4; ++g)
#pragma unroll
        for (int c = 0; c < 4; ++c)
          aw[g * 4 + c] = __shfl(alpha, g * 8 + hi * 4 + c, 64);
#pragma unroll
      for (int r = 0; r < 16; ++r) {
        const float a2 = aw[(r >> 2) * 4 + (r & 3)];
        oacc[0][r] *= a2; oacc[1][r] *= a2;
        oacc[2][r] *= a2; oacc[3][r] *= a2;
      }

      // P = exp2(s - m), row sum
      float ls = 0.f;
#pragma unroll
      for (int r = 0; r < 16; ++r) {
        const float p0 = __builtin_amdgcn_exp2f(s0[r] - m); s0[r] = p0; ls += p0;
        const float p1 = __builtin_amdgcn_exp2f(s1[r] - m); s1[r] = p1; ls += p1;
      }
      l += ls + __shfl_xor(ls, 32);

      // PV: 4 k-steps of 16 keys; A-words via cvt_pk + lane^32 exchange
#pragma unroll
      for (int t = 0; t < 4; ++t) {
        uint32_t a0, a1, b0, b1;
        if (t == 0) {
          a0 = pk2(s0[0], s0[1]); a1 = pk2(s0[2], s0[3]);
          b0 = pk2(s0[4], s0[5]); b1 = pk2(s0[6], s0[7]);
        } else if (t == 1) {
          a0 = pk2(s0[8], s0[9]); a1 = pk2(s0[10], s0[11]);
          b0 = pk2(s0[12], s0[13]); b1 = pk2(s0[14], s0[15]);
        } else if (t == 2) {
          a0 = pk2(s1[0], s1[1]); a1 = pk2(s1[2], s1[3]);
          b0 = pk2(s1[4], s1[5]); b1 = pk2(s1[6], s1[7]);
        } else {
          a0 = pk2(s1[8], s1[9]); a1 = pk2(s1[10], s1[11]);
          b0 = pk2(s1[12], s1[13]); b1 = pk2(s1[14], s1[15]);
        }
        const uint32_t sa0 = __shfl_xor(a0, 32), sa1 = __shfl_xor(a1, 32);
        const uint32_t sb0 = __shfl_xor(b0, 32), sb1 = __shfl_xor(b1, 32);
        union { uint32_t u[4]; bf16x8 v; } A;
        A.u[0] = hi ? sb0 : a0;
        A.u[1] = hi ? sb1 : a1;
        A.u[2] = hi ? b0 : sa0;
        A.u[3] = hi ? b1 : sa1;
#pragma unroll
        for (int d = 0; d < 4; ++d) {
          const int vrow = d * 32 + l31;
          const int vcb = (32 * t + 16 * hi) ^ ((vrow & 7) << 4);
          bf16x8 vf = *(const bf16x8*)(vb + vrow * 128 + vcb);
          oacc[d] = __builtin_amdgcn_mfma_f32_32x32x16_bf16(A.v, vf, oacc[d], 0, 0, 0);
        }
      }
    }
    __syncthreads();  // all reads of buf done before it is overwritten
  }

  // epilogue: 1/l redistribution + store
  const float linv = 1.0f / l;
  float lw[16];
#pragma unroll
  for (int g = 0; g < 4; ++g)
#pragma unroll
    for (int c = 0; c < 4; ++c)
      lw[g * 4 + c] = __shfl(linv, g * 8 + hi * 4 + c, 64);
  bf16* yb = Y + ((size_t)b * T) * 4096 + h * 128 + l31;
#pragma unroll
  for (int d = 0; d < 4; ++d)
#pragma unroll
    for (int r = 0; r < 16; ++r) {
      const int qp = (r & 3) + 8 * (r >> 2) + 4 * hi;
      const size_t trow = qc * 256 + w * 32 + qp;
      yb[trow * 4096 + d * 32] =
          __float2bfloat16(oacc[d][r] * lw[(r >> 2) * 4 + (r & 3)]);
    }
}

// ---------------- launch ----------------
extern "C" void kernel_launch(void* const* d_in, const int* in_sizes, int n_in,
                              void* d_out, int out_size, void* d_ws, size_t ws_size,
                              hipStream_t stream) {
  const float* x = (const float*)d_in[0];
  const float* fcos = (const float*)d_in[1];
  const float* fsin = (const float*)d_in[2];
  const float* wq = (const float*)d_in[3];
  const float* bq = (const float*)d_in[4];
  const float* wkv = (const float*)d_in[5];
  const float* bkv = (const float*)d_in[6];
  const float* wp = (const float*)d_in[7];
  const float* bp = (const float*)d_in[8];

  char* ws = (char*)d_ws;
  size_t off = 0;
  auto alloc = [&](size_t bytes) {
    char* p = ws + off;
    off += (bytes + 255) & ~(size_t)255;
    return p;
  };
  bf16* xb = (bf16*)alloc(16777216ull * 2);    // x bf16 [b][t][4096]
  bf16* wqb = (bf16*)alloc(16777216ull * 2);   // [4096][4096]; wkvb MUST follow
  bf16* wkvb = (bf16*)alloc(8388608ull * 2);   // [2048][4096] (contig after wqb)
  bf16* wpb = (bf16*)alloc(16777216ull * 2);
  bf16* qkv = (bf16*)alloc(25165824ull * 2);   // fused out [4096][6144]
  bf16* qr = (bf16*)alloc(16777216ull * 2);    // roped Q [b][h][t][128]
  bf16* kr = (bf16*)alloc(4194304ull * 2);     // roped K [b][kvh][t][128]
  bf16* vt = (bf16*)alloc(4194304ull * 2);     // V^T [b][kvh][128][t]
  float* bqkv = (float*)alloc(6144ull * 4);    // concat bias
  bf16* yb = qkv;                              // attn out aliases spent qkv

  k_cast<<<16384, 256, 0, stream>>>((const float4*)x, (uint2*)xb, 4194304);
  k_cast<<<16384, 256, 0, stream>>>((const float4*)wq, (uint2*)wqb, 4194304);
  k_cast<<<8192, 256, 0, stream>>>((const float4*)wkv, (uint2*)wkvb, 2097152);
  k_cast<<<16384, 256, 0, stream>>>((const float4*)wp, (uint2*)wpb, 4194304);
  k_bcat<<<24, 256, 0, stream>>>(bq, bkv, bqkv);

  // fused Q+KV GEMM: B = [wq; wkv] = 6144 rows, contiguous in ws
  k_gemm256<1><<<384, 512, 0, stream>>>(xb, wqb, bqkv, qkv, 4096, 6144, 4096, 24);

  k_rope_q<<<32768, 256, 0, stream>>>((const uint32_t*)qkv, fcos, fsin, (uint32_t*)qr);
  k_rope_k<<<8192, 256, 0, stream>>>((const uint32_t*)qkv, fcos, fsin, (uint32_t*)kr);
  k_vt<<<dim3(32, 16), 256, 0, stream>>>(qkv, vt);

  k_attn<<<512, 512, 0, stream>>>(qr, kr, vt, yb);

  k_gemm256<0><<<256, 512, 0, stream>>>(yb, wpb, bp, d_out, 4096, 4096, 4096, 16);
}

// Round 11
// 495.864 us; speedup vs baseline: 1.8853x; 1.0426x over previous
//
#include <hip/hip_runtime.h>
#include <hip/hip_bf16.h>
#include <stdint.h>

typedef __hip_bfloat16 bf16;
typedef __attribute__((ext_vector_type(8))) __bf16 bf16x8;
typedef __attribute__((ext_vector_type(4))) float f32x4;
typedef __attribute__((ext_vector_type(16))) float f32x16;

__device__ __forceinline__ void gld16(void* lds, const void* g) {
  __builtin_amdgcn_global_load_lds(
      (const __attribute__((address_space(1))) void*)(uintptr_t)(g),
      (__attribute__((address_space(3))) void*)(uint32_t)(uintptr_t)(lds),
      16, 0, 0);
}

__device__ __forceinline__ uint16_t f2bf(float f) {
  union { bf16 h; uint16_t u; } x; x.h = __float2bfloat16(f); return x.u;
}
__device__ __forceinline__ float bf2f(uint16_t v) {
  union { uint32_t u; float f; } x; x.u = ((uint32_t)v) << 16; return x.f;
}
__device__ __forceinline__ uint32_t pk2(float lo, float hi) {
  uint32_t r;
  asm("v_cvt_pk_bf16_f32 %0, %1, %2" : "=v"(r) : "v"(lo), "v"(hi));
  return r;
}

// ---------------- f32 -> bf16 cast (vectorized) ----------------
__global__ __launch_bounds__(256) void k_cast(const float4* __restrict__ in,
                                              uint2* __restrict__ out, int n4) {
  int i = blockIdx.x * 256 + threadIdx.x;
  if (i >= n4) return;
  float4 v = in[i];
  uint32_t a = ((uint32_t)f2bf(v.y) << 16) | f2bf(v.x);
  uint32_t b = ((uint32_t)f2bf(v.w) << 16) | f2bf(v.z);
  out[i] = make_uint2(a, b);
}

// ---------------- (MB64*64)x256 NT GEMM, counted-lgkm pipelined K-loop -----
// MB64=4: 256x256 tile (proj/Q). MB64=2: 128x256 tile (KV: grid 32x8=256 =
// exactly 1 block/CU -- fixes the 384-tile tail / half-idle-GPU problem).
// K-loop: one __syncthreads per K-tile (de-lockstep, r9); A-frag reads for
// phase p+1 issued into ping-pong regs BEFORE s_waitcnt lgkmcnt(2*MPP) so
// read latency hides under the MFMA burst (r10-verified on proj).
template <int OUT_BF16, int MB64>
__global__ __launch_bounds__(512, 2) void k_gemm256(
    const bf16* __restrict__ A, const bf16* __restrict__ B,
    const float* __restrict__ bias, void* __restrict__ C,
    int M, int N, int K, int gx) {
  constexpr int MPP = MB64 / 2;               // m-frags per phase (2 or 1)
  constexpr int MI = MB64 * 2;                // m-frags per wave (8 or 4)
  constexpr int ABYTES = MB64 * 8192;         // A bytes per slot
  constexpr int SLOT = ABYTES + 32768;        // slot stride (A | B 32KB)
  __shared__ __align__(16) char lds[2 * SLOT];
  const int tid = threadIdx.x;
  const int lane = tid & 63;
  const int w = tid >> 6;
  const int wm = w >> 2;
  const int wn = w & 3;
  const int lm = lane & 15;
  const int lg = lane >> 4;

  const int nwg = gridDim.x;
  const int cpx = nwg >> 3;
  const int bid0 = blockIdx.x;
  const int bid = (bid0 & 7) * cpx + (bid0 >> 3);
  const int bx = bid % gx;
  const int by = bid / gx;
  const size_t bm = (size_t)by * (MB64 * 64);
  const size_t bn = (size_t)bx * 256;

  const int srow = tid >> 3;
  const int scb = ((tid & 7) * 16) ^ ((srow & 7) << 4);
  const char* asrc[MB64];
  const char* bsrc[4];
#pragma unroll
  for (int j = 0; j < MB64; ++j)
    asrc[j] = (const char*)(A + (bm + j * 64 + srow) * K) + scb;
#pragma unroll
  for (int j = 0; j < 4; ++j)
    bsrc[j] = (const char*)(B + (bn + j * 64 + srow) * K) + scb;
  const int ldst = tid * 16;

  const int colb0 = (lg * 16) ^ ((lm & 7) << 4);
  const int colb1 = colb0 ^ 64;

  f32x4 acc[MI][4];
#pragma unroll
  for (int i = 0; i < MI; ++i)
#pragma unroll
    for (int j = 0; j < 4; ++j) acc[i][j] = (f32x4){0.f, 0.f, 0.f, 0.f};

  const int NT = K >> 6;

  // prologue: stage tile 0 -> slot 0
  {
    char* la = lds;
    char* lb = lds + ABYTES;
#pragma unroll
    for (int j = 0; j < MB64; ++j) gld16(la + j * 8192 + ldst, asrc[j]);
#pragma unroll
    for (int j = 0; j < 4; ++j) gld16(lb + j * 8192 + ldst, bsrc[j]);
  }
  __syncthreads();  // tile 0 landed

  for (int t = 0; t < NT; ++t) {
    const int slot = t & 1;
    const char* la = lds + slot * SLOT;
    const char* lb = la + ABYTES;

    // tile top: all B-frags + A-frags for phase 0
    bf16x8 bfrag[4][2];
#pragma unroll
    for (int ni = 0; ni < 4; ++ni) {
      const int br = wn * 64 + ni * 16 + lm;
      bfrag[ni][0] = *(const bf16x8*)(lb + br * 128 + colb0);
      bfrag[ni][1] = *(const bf16x8*)(lb + br * 128 + colb1);
    }
    bf16x8 afA[MPP][2], afB[MPP][2];
#pragma unroll
    for (int q = 0; q < MPP; ++q) {
      const int ar = wm * (MB64 * 32) + q * 16 + lm;
      afA[q][0] = *(const bf16x8*)(la + ar * 128 + colb0);
      afA[q][1] = *(const bf16x8*)(la + ar * 128 + colb1);
    }

    if (t + 1 < NT) {
      char* na = lds + (slot ^ 1) * SLOT;
      char* nb = na + ABYTES;
      const size_t ko = (size_t)(t + 1) * 128;
#pragma unroll
      for (int j = 0; j < MB64; ++j) gld16(na + j * 8192 + ldst, asrc[j] + ko);
#pragma unroll
      for (int j = 0; j < 4; ++j) gld16(nb + j * 8192 + ldst, bsrc[j] + ko);
    }

#pragma unroll
    for (int p = 0; p < 4; ++p) {
      auto& cur = (p & 1) ? afB : afA;
      auto& nxt = (p & 1) ? afA : afB;
      if (p < 3) {
#pragma unroll
        for (int q = 0; q < MPP; ++q) {
          const int ar = wm * (MB64 * 32) + ((p + 1) * MPP + q) * 16 + lm;
          nxt[q][0] = *(const bf16x8*)(la + ar * 128 + colb0);
          nxt[q][1] = *(const bf16x8*)(la + ar * 128 + colb1);
        }
        if constexpr (MPP == 2)
          asm volatile("s_waitcnt lgkmcnt(4)" ::: "memory");
        else
          asm volatile("s_waitcnt lgkmcnt(2)" ::: "memory");
      } else {
        asm volatile("s_waitcnt lgkmcnt(0)" ::: "memory");
      }
      __builtin_amdgcn_sched_barrier(0);
      __builtin_amdgcn_s_setprio(1);
#pragma unroll
      for (int q = 0; q < MPP; ++q) {
        bf16x8 a0 = cur[q][0], a1 = cur[q][1];
#pragma unroll
        for (int ni = 0; ni < 4; ++ni) {
          acc[p * MPP + q][ni] = __builtin_amdgcn_mfma_f32_16x16x32_bf16(
              a0, bfrag[ni][0], acc[p * MPP + q][ni], 0, 0, 0);
          acc[p * MPP + q][ni] = __builtin_amdgcn_mfma_f32_16x16x32_bf16(
              a1, bfrag[ni][1], acc[p * MPP + q][ni], 0, 0, 0);
        }
      }
      __builtin_amdgcn_s_setprio(0);
    }
    __syncthreads();  // t+1 landed + slot-reuse WAR done
  }

#pragma unroll
  for (int ni = 0; ni < 4; ++ni) {
    const size_t col = bn + wn * 64 + ni * 16 + lm;
    const float bv = bias[col];
#pragma unroll
    for (int mi = 0; mi < MI; ++mi) {
#pragma unroll
      for (int r = 0; r < 4; ++r) {
        const size_t row = bm + wm * (MB64 * 32) + mi * 16 + lg * 4 + r;
        const float v = acc[mi][ni][r] + bv;
        if (OUT_BF16)
          ((bf16*)C)[row * N + col] = __float2bfloat16(v);
        else
          ((float*)C)[row * N + col] = v;
      }
    }
  }
}

// ---------------- RoPE on Q: [b][t][h*128+d] -> [b][h][t][d] ----------------
__global__ __launch_bounds__(256) void k_rope_q(
    const uint32_t* __restrict__ qin, const float* __restrict__ fc,
    const float* __restrict__ fs, uint32_t* __restrict__ qout) {
  const int tid = blockIdx.x * 256 + threadIdx.x;
  const int i = tid & 63;
  const int h = (tid >> 6) & 31;
  const int t = (tid >> 11) & 2047;
  const int b = tid >> 22;
  const uint32_t u = qin[tid];
  const float t0 = bf2f((uint16_t)(u & 0xffff));
  const float t1 = bf2f((uint16_t)(u >> 16));
  const float c = fc[t * 64 + i];
  const float s = fs[t * 64 + i];
  const float r0 = t0 * c - t1 * s;
  const float r1 = t0 * s + t1 * c;
  const uint32_t o = ((uint32_t)f2bf(r1) << 16) | f2bf(r0);
  qout[(((size_t)(b * 32 + h)) * 2048 + t) * 64 + i] = o;
}

// ---------------- RoPE on K part of KV ----------------
__global__ __launch_bounds__(256) void k_rope_k(
    const uint32_t* __restrict__ kvin, const float* __restrict__ fc,
    const float* __restrict__ fs, uint32_t* __restrict__ kout) {
  const int tid = blockIdx.x * 256 + threadIdx.x;
  const int i = tid & 63;
  const int kvh = (tid >> 6) & 7;
  const int t = (tid >> 9) & 2047;
  const int b = tid >> 20;
  const uint32_t u = kvin[((size_t)(b * 2048 + t)) * 1024 + kvh * 64 + i];
  const float t0 = bf2f((uint16_t)(u & 0xffff));
  const float t1 = bf2f((uint16_t)(u >> 16));
  const float c = fc[t * 64 + i];
  const float s = fs[t * 64 + i];
  const float r0 = t0 * c - t1 * s;
  const float r1 = t0 * s + t1 * c;
  const uint32_t o = ((uint32_t)f2bf(r1) << 16) | f2bf(r0);
  kout[(((size_t)(b * 8 + kvh)) * 2048 + t) * 64 + i] = o;
}

// ---------------- V transpose -> [b][kvh][d][t] ----------------
__global__ __launch_bounds__(256) void k_vt(const bf16* __restrict__ kv,
                                            bf16* __restrict__ vt) {
  __shared__ __align__(16) bf16 tile[64][130];
  const int bh = blockIdx.y;
  const int b = bh >> 3, kvh = bh & 7;
  const int t0 = blockIdx.x * 64;
  const int tid = threadIdx.x;
  const int d0 = (tid & 15) * 8;
  const int tr = tid >> 4;
#pragma unroll
  for (int j = 0; j < 4; ++j) {
    const int trow = tr + j * 16;
    const bf16* src =
        kv + ((size_t)(b * 2048) + t0 + trow) * 2048 + 1024 + kvh * 128 + d0;
    uint4 v = *(const uint4*)src;
    uint32_t* dst = (uint32_t*)&tile[trow][d0];
    dst[0] = v.x; dst[1] = v.y; dst[2] = v.z; dst[3] = v.w;
  }
  __syncthreads();
  const int d = tid >> 1;
  const int th = (tid & 1) * 32;
  uint4* out = (uint4*)(vt + (((size_t)bh) * 128 + d) * 2048 + t0 + th);
  union { bf16 h; uint16_t u; } cv;
#pragma unroll
  for (int j = 0; j < 4; ++j) {
    uint32_t wds[4];
#pragma unroll
    for (int p = 0; p < 4; ++p) {
      cv.h = tile[th + j * 8 + p * 2][d];
      uint32_t lo = cv.u;
      cv.h = tile[th + j * 8 + p * 2 + 1][d];
      wds[p] = lo | ((uint32_t)cv.u << 16);
    }
    uint4 val; val.x = wds[0]; val.y = wds[1]; val.z = wds[2]; val.w = wds[3];
    out[j] = val;
  }
}

// ---------------- causal GQA flash attention, 8-warp 32x32 swapped-QK^T ----
// SAFE-SYNC (round-7 verified form, unchanged).
__global__ __launch_bounds__(512) void k_attn(
    const bf16* __restrict__ Q, const bf16* __restrict__ Kr,
    const bf16* __restrict__ Vt, bf16* __restrict__ Y) {
  constexpr int T = 2048;
  __shared__ __align__(16) char lds[65536];  // [2][K 16KB | V 16KB]
  const int tid = threadIdx.x;
  const int lane = tid & 63;
  const int w = tid >> 6;
  const int l31 = lane & 31;
  const int hi = lane >> 5;

  const int n = blockIdx.x;
  const int qc = 7 - (n >> 6);  // heavy-first
  const int bh = n & 63;
  const int b = bh >> 5, h = bh & 31, kvh = h >> 2;

  const int qrow = qc * 256 + w * 32 + l31;
  const int qmaxw = qc * 256 + w * 32 + 31;
  const int NT = qc * 4 + 4;

  const bf16* qptr = Q + (((size_t)(b * 32 + h)) * T + qrow) * 128 + hi * 8;
  bf16x8 qf[8];
#pragma unroll
  for (int kt = 0; kt < 8; ++kt) qf[kt] = *(const bf16x8*)(qptr + kt * 16);

  const char* kg = (const char*)(Kr + ((size_t)(b * 8 + kvh)) * T * 128);
  const char* vg = (const char*)(Vt + ((size_t)(b * 8 + kvh)) * 128 * T);
  const char* ksrc[2];
  const char* vsrc[2];
  int kdst[2], vdst[2];
#pragma unroll
  for (int j = 0; j < 2; ++j) {
    const int o = j * 8192 + tid * 16;
    const int krow = o >> 8, kin = o & 255;
    ksrc[j] = kg + (size_t)krow * 256 + (kin ^ ((krow & 15) << 4));
    kdst[j] = o;
    const int vrow = o >> 7, vin = o & 127;
    vsrc[j] = vg + (size_t)vrow * (T * 2) + (vin ^ ((vrow & 7) << 4));
    vdst[j] = 16384 + o;
  }

  f32x16 oacc[4];
#pragma unroll
  for (int d = 0; d < 4; ++d)
#pragma unroll
    for (int r = 0; r < 16; ++r) oacc[d][r] = 0.f;
  float m = -1e30f, l = 0.f;
  const float c1 = 0.08838834764831845f * 1.44269504089f;  // scale*log2e

  // prologue: stage tile 0 -> buf 0
#pragma unroll
  for (int j = 0; j < 2; ++j) {
    gld16(lds + kdst[j], ksrc[j]);
    gld16(lds + vdst[j], vsrc[j]);
  }

  for (int it = 0; it < NT; ++it) {
    const int buf = it & 1;
    __syncthreads();  // drains all vmcnt (tile-it staging) + block barrier

    if (it + 1 < NT) {  // stage next tile into the other buffer (overlaps)
      const int nb = buf ^ 1;
      const size_t ko = (size_t)(it + 1) * 16384;
      const size_t vo = (size_t)(it + 1) * 128;
#pragma unroll
      for (int j = 0; j < 2; ++j) {
        gld16(lds + nb * 32768 + kdst[j], ksrc[j] + ko);
        gld16(lds + nb * 32768 + vdst[j], vsrc[j] + vo);
      }
    }

    const int kt0 = it * 64;
    if (kt0 <= qmaxw) {  // warp-uniform: skip fully-masked tiles
      const char* kb = lds + buf * 32768;
      const char* vb = kb + 16384;

      // S^T = K Q^T  (two 32-key subtiles)
      f32x16 s0, s1;
#pragma unroll
      for (int r = 0; r < 16; ++r) { s0[r] = 0.f; s1[r] = 0.f; }
      const int kswz = (l31 & 15) << 4;
#pragma unroll
      for (int kt = 0; kt < 8; ++kt) {
        const int cb = (kt * 32 + hi * 16) ^ kswz;
        bf16x8 kf0 = *(const bf16x8*)(kb + l31 * 256 + cb);
        bf16x8 kf1 = *(const bf16x8*)(kb + (32 + l31) * 256 + cb);
        s0 = __builtin_amdgcn_mfma_f32_32x32x16_bf16(kf0, qf[kt], s0, 0, 0, 0);
        s1 = __builtin_amdgcn_mfma_f32_32x32x16_bf16(kf1, qf[kt], s1, 0, 0, 0);
      }

      // mask + scale (log2 units) + row max
      float tmax = -1e30f;
#pragma unroll
      for (int r = 0; r < 16; ++r) {
        const int key0 = kt0 + (r & 3) + 8 * (r >> 2) + 4 * hi;
        float v0 = s0[r] * c1;
        v0 = (key0 <= qrow) ? v0 : -1e30f;
        s0[r] = v0; tmax = fmaxf(tmax, v0);
        float v1 = s1[r] * c1;
        v1 = (key0 + 32 <= qrow) ? v1 : -1e30f;
        s1[r] = v1; tmax = fmaxf(tmax, v1);
      }
      tmax = fmaxf(tmax, __shfl_xor(tmax, 32));

      // online update, unconditional rescale
      const float mn = fmaxf(m, tmax);
      const float alpha = __builtin_amdgcn_exp2f(m - mn);
      m = mn;
      l *= alpha;
      float aw[16];
#pragma unroll
      for (int g = 0; g < 4; ++g)
#pragma unroll
        for (int c = 0; c < 4; ++c)
          aw[g * 4 + c] = __shfl(alpha, g * 8 + hi * 4 + c, 64);
#pragma unroll
      for (int r = 0; r < 16; ++r) {
        const float a2 = aw[(r >> 2) * 4 + (r & 3)];
        oacc[0][r] *= a2; oacc[1][r] *= a2;
        oacc[2][r] *= a2; oacc[3][r] *= a2;
      }

      // P = exp2(s - m), row sum
      float ls = 0.f;
#pragma unroll
      for (int r = 0; r < 16; ++r) {
        const float p0 = __builtin_amdgcn_exp2f(s0[r] - m); s0[r] = p0; ls += p0;
        const float p1 = __builtin_amdgcn_exp2f(s1[r] - m); s1[r] = p1; ls += p1;
      }
      l += ls + __shfl_xor(ls, 32);

      // PV: 4 k-steps of 16 keys; A-words via cvt_pk + lane^32 exchange
#pragma unroll
      for (int t = 0; t < 4; ++t) {
        uint32_t a0, a1, b0, b1;
        if (t == 0) {
          a0 = pk2(s0[0], s0[1]); a1 = pk2(s0[2], s0[3]);
          b0 = pk2(s0[4], s0[5]); b1 = pk2(s0[6], s0[7]);
        } else if (t == 1) {
          a0 = pk2(s0[8], s0[9]); a1 = pk2(s0[10], s0[11]);
          b0 = pk2(s0[12], s0[13]); b1 = pk2(s0[14], s0[15]);
        } else if (t == 2) {
          a0 = pk2(s1[0], s1[1]); a1 = pk2(s1[2], s1[3]);
          b0 = pk2(s1[4], s1[5]); b1 = pk2(s1[6], s1[7]);
        } else {
          a0 = pk2(s1[8], s1[9]); a1 = pk2(s1[10], s1[11]);
          b0 = pk2(s1[12], s1[13]); b1 = pk2(s1[14], s1[15]);
        }
        const uint32_t sa0 = __shfl_xor(a0, 32), sa1 = __shfl_xor(a1, 32);
        const uint32_t sb0 = __shfl_xor(b0, 32), sb1 = __shfl_xor(b1, 32);
        union { uint32_t u[4]; bf16x8 v; } A;
        A.u[0] = hi ? sb0 : a0;
        A.u[1] = hi ? sb1 : a1;
        A.u[2] = hi ? b0 : sa0;
        A.u[3] = hi ? b1 : sa1;
#pragma unroll
        for (int d = 0; d < 4; ++d) {
          const int vrow = d * 32 + l31;
          const int vcb = (32 * t + 16 * hi) ^ ((vrow & 7) << 4);
          bf16x8 vf = *(const bf16x8*)(vb + vrow * 128 + vcb);
          oacc[d] = __builtin_amdgcn_mfma_f32_32x32x16_bf16(A.v, vf, oacc[d], 0, 0, 0);
        }
      }
    }
    __syncthreads();  // all reads of buf done before it is overwritten
  }

  // epilogue: 1/l redistribution + store
  const float linv = 1.0f / l;
  float lw[16];
#pragma unroll
  for (int g = 0; g < 4; ++g)
#pragma unroll
    for (int c = 0; c < 4; ++c)
      lw[g * 4 + c] = __shfl(linv, g * 8 + hi * 4 + c, 64);
  bf16* yb = Y + ((size_t)b * T) * 4096 + h * 128 + l31;
#pragma unroll
  for (int d = 0; d < 4; ++d)
#pragma unroll
    for (int r = 0; r < 16; ++r) {
      const int qp = (r & 3) + 8 * (r >> 2) + 4 * hi;
      const size_t trow = qc * 256 + w * 32 + qp;
      yb[trow * 4096 + d * 32] =
          __float2bfloat16(oacc[d][r] * lw[(r >> 2) * 4 + (r & 3)]);
    }
}

// ---------------- launch ----------------
extern "C" void kernel_launch(void* const* d_in, const int* in_sizes, int n_in,
                              void* d_out, int out_size, void* d_ws, size_t ws_size,
                              hipStream_t stream) {
  const float* x = (const float*)d_in[0];
  const float* fcos = (const float*)d_in[1];
  const float* fsin = (const float*)d_in[2];
  const float* wq = (const float*)d_in[3];
  const float* bq = (const float*)d_in[4];
  const float* wkv = (const float*)d_in[5];
  const float* bkv = (const float*)d_in[6];
  const float* wp = (const float*)d_in[7];
  const float* bp = (const float*)d_in[8];

  char* ws = (char*)d_ws;
  size_t off = 0;
  auto alloc = [&](size_t bytes) {
    char* p = ws + off;
    off += (bytes + 255) & ~(size_t)255;
    return p;
  };
  bf16* xb = (bf16*)alloc(16777216ull * 2);    // x bf16 [b][t][4096]
  bf16* wqb = (bf16*)alloc(16777216ull * 2);   // [4096][4096]
  bf16* wkvb = (bf16*)alloc(8388608ull * 2);   // [2048][4096]
  bf16* wpb = (bf16*)alloc(16777216ull * 2);
  bf16* qb = (bf16*)alloc(16777216ull * 2);    // q pre-rope; reused as Y
  bf16* kvb = (bf16*)alloc(8388608ull * 2);    // kv pre-rope [b][t][2048]
  bf16* qr = (bf16*)alloc(16777216ull * 2);    // roped Q [b][h][t][128]
  bf16* kr = (bf16*)alloc(4194304ull * 2);     // roped K [b][kvh][t][128]
  bf16* vt = (bf16*)alloc(4194304ull * 2);     // V^T [b][kvh][128][t]
  bf16* yb = qb;                               // attn out aliases qb

  k_cast<<<16384, 256, 0, stream>>>((const float4*)x, (uint2*)xb, 4194304);
  k_cast<<<16384, 256, 0, stream>>>((const float4*)wq, (uint2*)wqb, 4194304);
  k_cast<<<8192, 256, 0, stream>>>((const float4*)wkv, (uint2*)wkvb, 2097152);
  k_cast<<<16384, 256, 0, stream>>>((const float4*)wp, (uint2*)wpb, 4194304);

  // Q: 256x256 tile, grid 256 (1/CU exact). KV: 128x256 tile, grid 32x8=256.
  k_gemm256<1, 4><<<256, 512, 0, stream>>>(xb, wqb, bq, qb, 4096, 4096, 4096, 16);
  k_gemm256<1, 2><<<256, 512, 0, stream>>>(xb, wkvb, bkv, kvb, 4096, 2048, 4096, 8);

  k_rope_q<<<32768, 256, 0, stream>>>((const uint32_t*)qb, fcos, fsin, (uint32_t*)qr);
  k_rope_k<<<8192, 256, 0, stream>>>((const uint32_t*)kvb, fcos, fsin, (uint32_t*)kr);
  k_vt<<<dim3(32, 16), 256, 0, stream>>>(kvb, vt);

  k_attn<<<512, 512, 0, stream>>>(qr, kr, vt, yb);

  k_gemm256<0, 4><<<256, 512, 0, stream>>>(yb, wpb, bp, d_out, 4096, 4096, 4096, 16);
}